// Round 1
// baseline (5558.606 us; speedup 1.0000x reference)
//
#include <hip/hip_runtime.h>
#include <hip/hip_bf16.h>

// ---------------------------------------------------------------------------
// THEGCNModel: temporal GNN.
//   Phase 1: per-edge MLP (66->33->17) on [x_i | x_j | cos-basis], segment-mean
//            into dst, h = (x + mean) @ proj (17->64).
//   Phase 2: L=2 layers: per-edge MLP (128->64 relu ->64 tanh), msg=(2p-1)*h_i,
//            h += segment_mean(msg, dst), h = relu(BN(h)).
//   Classifier: 3 linears + 2 BNs on first `batch` rows.
// All f32 this round (correctness baseline). batch taken from out_size.
// ---------------------------------------------------------------------------

__device__ __forceinline__ float tanh_factor(float u) {
  // 2*tanh(u) - 1 == 1 - 4/(exp(2u)+1); exp->inf handled (4/inf = 0)
  float e = __expf(2.0f * u);
  return 1.0f - 4.0f / (e + 1.0f);
}

__device__ __forceinline__ void atomic_add_f32(float* p, float v) {
  unsafeAtomicAdd(p, v);  // native global_atomic_add_f32 on gfx950
}

// ---------------------------------------------------------------------------
// Phase 1 edge kernel: one thread per edge.
// ---------------------------------------------------------------------------
__global__ __launch_bounds__(256) void phase1_edge(
    const float* __restrict__ x, const int* __restrict__ ei,
    const float* __restrict__ dts, const float* __restrict__ freq,
    const float* __restrict__ phs,
    const float* __restrict__ W1, const float* __restrict__ b1,
    const float* __restrict__ W2, const float* __restrict__ b2,
    float* __restrict__ accum, float* __restrict__ counts, int E)
{
  int e = blockIdx.x * 256 + threadIdx.x;
  if (e >= E) return;
  int srcn = ei[e];
  int dstn = ei[E + e];

  float xi[17], xj[17];
#pragma unroll
  for (int c = 0; c < 17; c++) { xi[c] = x[dstn * 17 + c]; xj[c] = x[srcn * 17 + c]; }

  float dt = dts[e];
  float rel[32];
#pragma unroll
  for (int t = 0; t < 32; t++) rel[t] = __cosf(fmaf(dt, freq[t], phs[t]));

  float out[17];
#pragma unroll
  for (int c = 0; c < 17; c++) out[c] = b2[c];

  // stream hidden units (j uniform across wave -> scalar weight loads)
#pragma unroll 3
  for (int j = 0; j < 33; j++) {
    float acc = b1[j];
#pragma unroll
    for (int k = 0; k < 17; k++) acc = fmaf(xi[k], W1[k * 33 + j], acc);
#pragma unroll
    for (int k = 0; k < 17; k++) acc = fmaf(xj[k], W1[(17 + k) * 33 + j], acc);
#pragma unroll
    for (int k = 0; k < 32; k++) acc = fmaf(rel[k], W1[(34 + k) * 33 + j], acc);
    acc = fmaxf(acc, 0.0f);
#pragma unroll
    for (int c = 0; c < 17; c++) out[c] = fmaf(acc, W2[j * 17 + c], out[c]);
  }

#pragma unroll
  for (int c = 0; c < 17; c++) {
    float f = tanh_factor(out[c]);
    atomic_add_f32(&accum[dstn * 17 + c], f * xi[c]);
  }
  atomic_add_f32(&counts[dstn], 1.0f);
}

// ---------------------------------------------------------------------------
// Phase 1 node kernel: h[n] = (x[n] + accum[n]/max(cnt,1)) @ projW + projb.
// 4 nodes per block of 256 (64 cols each); coalesced h stores.
// ---------------------------------------------------------------------------
__global__ __launch_bounds__(256) void phase1_node(
    const float* __restrict__ x, const float* __restrict__ acc1,
    const float* __restrict__ counts, const float* __restrict__ Wp,
    const float* __restrict__ bp, float* __restrict__ h, int N)
{
  __shared__ float s0[4][20];
  const int t = threadIdx.x;
  const int nb = blockIdx.x << 2;
  if (t < 68) {
    int nl = t / 17, c = t % 17;
    int n = nb + nl;
    float v = 0.0f;
    if (n < N) {
      float cnt = fmaxf(counts[n], 1.0f);
      v = x[n * 17 + c] + acc1[n * 17 + c] / cnt;
    }
    s0[nl][c] = v;
  }
  __syncthreads();
  int nl = t >> 6, j = t & 63;
  int n = nb + nl;
  if (n < N) {
    float acc = bp[j];
#pragma unroll
    for (int c = 0; c < 17; c++) acc = fmaf(s0[nl][c], Wp[c * 64 + j], acc);
    h[n * 64 + j] = acc;
  }
}

// ---------------------------------------------------------------------------
// Phase 2 edge kernel: tiles of 64 edges, 256 threads, 4x4 register tiles.
// LDS 51.7KB -> 3 blocks/CU. Weights re-staged per tile (L1/L2-hot).
// Buffers padded to 68 floats/row: a-reads land 2-way (free) on banks.
// ---------------------------------------------------------------------------
__device__ __forceinline__ void gemm64(float acc[4][4],
    const float (&A)[64][68], const float (&Wm)[64][64], int eg, int c4)
{
#pragma unroll
  for (int k = 0; k < 64; k += 4) {
    float a[4][4], w[4][4];
#pragma unroll
    for (int e = 0; e < 4; e++) {
      const float4 v = *(const float4*)&A[eg + 16 * e][k];
      a[e][0] = v.x; a[e][1] = v.y; a[e][2] = v.z; a[e][3] = v.w;
    }
#pragma unroll
    for (int kk = 0; kk < 4; kk++) {
      const float4 v = *(const float4*)&Wm[k + kk][c4];
      w[kk][0] = v.x; w[kk][1] = v.y; w[kk][2] = v.z; w[kk][3] = v.w;
    }
#pragma unroll
    for (int e = 0; e < 4; e++)
#pragma unroll
      for (int kk = 0; kk < 4; kk++)
#pragma unroll
        for (int c = 0; c < 4; c++)
          acc[e][c] = fmaf(a[e][kk], w[kk][c], acc[e][c]);
  }
}

__global__ __launch_bounds__(256) void phase2_edge(
    const float* __restrict__ h, const int* __restrict__ ei,
    const float* __restrict__ W1, const float* __restrict__ b1,
    const float* __restrict__ W2, const float* __restrict__ b2,
    float* __restrict__ accum, int E, int ntiles)
{
  __shared__ float sHi[64][68];   // h[dst] tile (kept for epilogue)
  __shared__ float sB[64][68];    // h[src] tile, then hidden tile
  __shared__ float sW[64][64];    // current 64x64 weight slab
  __shared__ float sbb1[64], sbb2[64];

  const int t = threadIdx.x;
  if (t < 64) { sbb1[t] = b1[t]; sbb2[t] = b2[t]; }
  const int eg = t & 15;           // edge sub-row (consecutive lanes -> rows)
  const int c4 = (t >> 4) << 2;    // output column group

  for (int tile = blockIdx.x; tile < ntiles; tile += gridDim.x) {
    const int eb = tile << 6;

    // stage h_i (dst rows) and W1 rows 0..63
#pragma unroll
    for (int i = 0; i < 4; i++) {
      int g = t + i * 256;
      int r = g >> 4, k4 = (g & 15) << 2;
      int er = eb + r; if (er > E - 1) er = E - 1;
      int node = ei[E + er];                       // dst
      *(float4*)&sHi[r][k4] = *(const float4*)&h[node * 64 + k4];
      *(float4*)&sW[r][k4] = *(const float4*)&W1[r * 64 + k4];
    }
    __syncthreads();                               // 1

    float acc[4][4];
#pragma unroll
    for (int e = 0; e < 4; e++)
#pragma unroll
      for (int c = 0; c < 4; c++) acc[e][c] = sbb1[c4 + c];

    gemm64(acc, sHi, sW, eg, c4);                  // pass A: h_i @ W1[0:64]
    __syncthreads();                               // 2

    // stage h_j (src rows) and W1 rows 64..127
#pragma unroll
    for (int i = 0; i < 4; i++) {
      int g = t + i * 256;
      int r = g >> 4, k4 = (g & 15) << 2;
      int er = eb + r; if (er > E - 1) er = E - 1;
      int node = ei[er];                           // src
      *(float4*)&sB[r][k4] = *(const float4*)&h[node * 64 + k4];
      *(float4*)&sW[r][k4] = *(const float4*)&W1[(64 + r) * 64 + k4];
    }
    __syncthreads();                               // 3

    gemm64(acc, sB, sW, eg, c4);                   // pass B: h_j @ W1[64:128]
    __syncthreads();                               // 4

    // hidden = relu(acc) -> sB ; stage W2
#pragma unroll
    for (int e = 0; e < 4; e++)
#pragma unroll
      for (int c = 0; c < 4; c++)
        sB[eg + 16 * e][c4 + c] = fmaxf(acc[e][c], 0.0f);
#pragma unroll
    for (int i = 0; i < 4; i++) {
      int g = t + i * 256;
      int r = g >> 4, k4 = (g & 15) << 2;
      *(float4*)&sW[r][k4] = *(const float4*)&W2[r * 64 + k4];
    }
    __syncthreads();                               // 5

#pragma unroll
    for (int e = 0; e < 4; e++)
#pragma unroll
      for (int c = 0; c < 4; c++) acc[e][c] = sbb2[c4 + c];

    gemm64(acc, sB, sW, eg, c4);                   // hidden @ W2

    // epilogue: msg = (2*tanh(u)-1) * h_i, scatter-add to accum[dst]
#pragma unroll
    for (int e = 0; e < 4; e++) {
      int row = eg + 16 * e;
      if (eb + row < E) {
        int dn = ei[E + eb + row];
#pragma unroll
        for (int c = 0; c < 4; c++) {
          float f = tanh_factor(acc[e][c]);
          atomic_add_f32(&accum[dn * 64 + c4 + c], f * sHi[row][c4 + c]);
        }
      }
    }
    __syncthreads();                               // 6: protect LDS for next tile
  }
}

// ---------------------------------------------------------------------------
// Node update + BN statistics (sum, sumsq per column).
// ---------------------------------------------------------------------------
__global__ __launch_bounds__(256) void node_update_bn(
    float* __restrict__ h, const float* __restrict__ accum,
    const float* __restrict__ counts, float* __restrict__ bns,
    float* __restrict__ bnq, int N)
{
  const int t = threadIdx.x;
  float ls = 0.0f, lq = 0.0f;
  int total = N * 64;
  for (int idx = blockIdx.x * 256 + t; idx < total; idx += gridDim.x * 256) {
    int n = idx >> 6;
    float cnt = fmaxf(counts[n], 1.0f);
    float v = h[idx] + accum[idx] / cnt;
    h[idx] = v;
    ls += v; lq += v * v;
  }
  __shared__ float ss[256], sq[256];
  ss[t] = ls; sq[t] = lq;
  __syncthreads();
  if (t < 64) {
    float s = ss[t] + ss[t + 64] + ss[t + 128] + ss[t + 192];
    float q = sq[t] + sq[t + 64] + sq[t + 128] + sq[t + 192];
    atomic_add_f32(&bns[t], s);
    atomic_add_f32(&bnq[t], q);
  }
}

// ---------------------------------------------------------------------------
// BN apply + relu (in place). cmask = C-1 (C power of 2).
// ---------------------------------------------------------------------------
__global__ __launch_bounds__(256) void bn_apply_relu(
    float* __restrict__ d, const float* __restrict__ bns,
    const float* __restrict__ bnq, const float* __restrict__ gam,
    const float* __restrict__ bet, int total, int cmask, float invRows)
{
  for (int idx = blockIdx.x * 256 + threadIdx.x; idx < total;
       idx += gridDim.x * 256) {
    int c = idx & cmask;
    float m = bns[c] * invRows;
    float var = bnq[c] * invRows - m * m;
    float sc = gam[c] * rsqrtf(var + 1e-5f);
    d[idx] = fmaxf((d[idx] - m) * sc + bet[c], 0.0f);
  }
}

// ---------------------------------------------------------------------------
// Classifier matmul (rows x K @ K x C) + bias, with BN stats.
// in row stride == K. C = 1<<cshift.
// ---------------------------------------------------------------------------
__global__ __launch_bounds__(256) void clf_mm_bn(
    const float* __restrict__ in, const float* __restrict__ W,
    const float* __restrict__ b, float* __restrict__ out,
    float* __restrict__ bns, float* __restrict__ bnq,
    int rows, int K, int cshift)
{
  const int t = threadIdx.x;
  const int C = 1 << cshift;
  int total = rows << cshift;
  float ls = 0.0f, lq = 0.0f;
  for (int idx = blockIdx.x * 256 + t; idx < total; idx += gridDim.x * 256) {
    int n = idx >> cshift;
    int c = idx & (C - 1);
    float acc = b[c];
#pragma unroll 8
    for (int k = 0; k < K; k++) acc = fmaf(in[n * K + k], W[(k << cshift) + c], acc);
    out[idx] = acc;
    ls += acc; lq += acc * acc;
  }
  __shared__ float ss[256], sq[256];
  ss[t] = ls; sq[t] = lq;
  __syncthreads();
  if (t < C) {
    float s = 0.0f, q = 0.0f;
    for (int i = t; i < 256; i += C) { s += ss[i]; q += sq[i]; }
    atomic_add_f32(&bns[t], s);
    atomic_add_f32(&bnq[t], q);
  }
}

__global__ __launch_bounds__(256) void clf_final(
    const float* __restrict__ z2, const float* __restrict__ W3,
    const float* __restrict__ b3, float* __restrict__ out, int rows)
{
  int n = blockIdx.x * 256 + threadIdx.x;
  if (n >= rows) return;
  float acc = b3[0];
#pragma unroll
  for (int k = 0; k < 32; k++) acc = fmaf(z2[n * 32 + k], W3[k], acc);
  out[n] = acc;
}

// ---------------------------------------------------------------------------
extern "C" void kernel_launch(void* const* d_in, const int* in_sizes, int n_in,
                              void* d_out, int out_size, void* d_ws, size_t ws_size,
                              hipStream_t stream)
{
  const float* x    = (const float*)d_in[0];
  const int*   ei   = (const int*)  d_in[1];
  const float* dts  = (const float*)d_in[2];
  // d_in[3] = batch_size (device scalar) -- batch == out_size
  const float* freq = (const float*)d_in[4];
  const float* phs  = (const float*)d_in[5];
  const float* tW1  = (const float*)d_in[6];
  const float* tb1  = (const float*)d_in[7];
  const float* tW2  = (const float*)d_in[8];
  const float* tb2  = (const float*)d_in[9];
  const float* pW   = (const float*)d_in[10];
  const float* pb   = (const float*)d_in[11];
  const float* sW1  = (const float*)d_in[12];
  const float* sb1  = (const float*)d_in[13];
  const float* sW2  = (const float*)d_in[14];
  const float* sb2  = (const float*)d_in[15];
  const float* bng  = (const float*)d_in[16];
  const float* bnb  = (const float*)d_in[17];
  const float* cW1  = (const float*)d_in[18];
  const float* cb1  = (const float*)d_in[19];
  const float* cg1  = (const float*)d_in[20];
  const float* cbb1 = (const float*)d_in[21];
  const float* cW2  = (const float*)d_in[22];
  const float* cb2  = (const float*)d_in[23];
  const float* cg2  = (const float*)d_in[24];
  const float* cbb2 = (const float*)d_in[25];
  const float* cW3  = (const float*)d_in[26];
  const float* cb3  = (const float*)d_in[27];
  float* out = (float*)d_out;

  const int N = in_sizes[0] / 17;
  const int E = in_sizes[1] / 2;
  const int B = out_size;

  // workspace layout (floats)
  float* ws     = (float*)d_ws;
  float* h      = ws;                           // N*64
  float* acc2   = h      + (size_t)N * 64;      // N*64
  float* counts = acc2   + (size_t)N * 64;      // N
  float* acc1   = counts + (size_t)N;           // N*17 (later reused as z1/z2)
  float* z1     = acc1;                         // B*64
  float* z2     = z1     + (size_t)B * 64;      // B*32
  float* bns    = acc1   + (size_t)N * 17;      // 64
  float* bnq    = bns + 64;                     // 64
  size_t needed = ((size_t)N * 64 * 2 + N + (size_t)N * 17 + 128) * 4;
  if (ws_size < needed) return;  // fail visibly (output stays poisoned)

  const int ntiles = (E + 63) / 64;

  // phase 1
  hipMemsetAsync(counts, 0, (size_t)(N + (size_t)N * 17) * 4, stream);
  phase1_edge<<<(E + 255) / 256, 256, 0, stream>>>(
      x, ei, dts, freq, phs, tW1, tb1, tW2, tb2, acc1, counts, E);
  phase1_node<<<(N + 3) / 4, 256, 0, stream>>>(x, acc1, counts, pW, pb, h, N);

  // phase 2: L = 2 message-passing + BN layers
  for (int l = 0; l < 2; l++) {
    hipMemsetAsync(acc2, 0, (size_t)N * 64 * 4, stream);
    hipMemsetAsync(bns, 0, 128 * 4, stream);
    phase2_edge<<<768, 256, 0, stream>>>(
        h, ei, sW1 + (size_t)l * 128 * 64, sb1 + l * 64,
        sW2 + (size_t)l * 64 * 64, sb2 + l * 64, acc2, E, ntiles);
    node_update_bn<<<1024, 256, 0, stream>>>(h, acc2, counts, bns, bnq, N);
    bn_apply_relu<<<2048, 256, 0, stream>>>(
        h, bns, bnq, bng + l * 64, bnb + l * 64, N * 64, 63, 1.0f / (float)N);
  }

  // classifier on first B rows of h
  hipMemsetAsync(bns, 0, 128 * 4, stream);
  clf_mm_bn<<<2500, 256, 0, stream>>>(h, cW1, cb1, z1, bns, bnq, B, 64, 6);
  bn_apply_relu<<<1024, 256, 0, stream>>>(z1, bns, bnq, cg1, cbb1, B * 64, 63,
                                          1.0f / (float)B);
  hipMemsetAsync(bns, 0, 128 * 4, stream);
  clf_mm_bn<<<1250, 256, 0, stream>>>(z1, cW2, cb2, z2, bns, bnq, B, 64, 5);
  bn_apply_relu<<<512, 256, 0, stream>>>(z2, bns, bnq, cg2, cbb2, B * 32, 31,
                                         1.0f / (float)B);
  clf_final<<<(B + 255) / 256, 256, 0, stream>>>(z2, cW3, cb3, out, B);
}

// Round 2
// 2608.036 us; speedup vs baseline: 2.1313x; 2.1313x over previous
//
#include <hip/hip_runtime.h>
#include <hip/hip_bf16.h>

// ---------------------------------------------------------------------------
// THEGCNModel — R2: phase2 edge MLP moved to bf16 MFMA (16x16x32).
//   Weights pre-converted to bf16 transposed [n][k]; h kept in f32 + bf16.
//   Atomic f32 scatter unchanged (target for next round if WRITE-bound).
// ---------------------------------------------------------------------------

typedef float  f32x4 __attribute__((ext_vector_type(4)));
typedef short  s16x8 __attribute__((ext_vector_type(8)));

__device__ __forceinline__ float tanh_factor(float u) {
  // 2*tanh(u) - 1 == 1 - 4/(exp(2u)+1)
  float e = __expf(2.0f * u);
  return 1.0f - 4.0f / (e + 1.0f);
}

__device__ __forceinline__ void atomic_add_f32(float* p, float v) {
  unsafeAtomicAdd(p, v);  // native global_atomic_add_f32 on gfx950
}

__device__ __forceinline__ unsigned short f2bf(float f) {
  __hip_bfloat16 b = __float2bfloat16(f);
  return *(unsigned short*)&b;
}
__device__ __forceinline__ float bf2f(unsigned short u) {
  unsigned int v = ((unsigned int)u) << 16;
  return *(float*)&v;
}

// ---------------------------------------------------------------------------
// Phase 1 edge kernel: one thread per edge (unchanged from R1).
// ---------------------------------------------------------------------------
__global__ __launch_bounds__(256) void phase1_edge(
    const float* __restrict__ x, const int* __restrict__ ei,
    const float* __restrict__ dts, const float* __restrict__ freq,
    const float* __restrict__ phs,
    const float* __restrict__ W1, const float* __restrict__ b1,
    const float* __restrict__ W2, const float* __restrict__ b2,
    float* __restrict__ accum, float* __restrict__ counts, int E)
{
  int e = blockIdx.x * 256 + threadIdx.x;
  if (e >= E) return;
  int srcn = ei[e];
  int dstn = ei[E + e];

  float xi[17], xj[17];
#pragma unroll
  for (int c = 0; c < 17; c++) { xi[c] = x[dstn * 17 + c]; xj[c] = x[srcn * 17 + c]; }

  float dt = dts[e];
  float rel[32];
#pragma unroll
  for (int t = 0; t < 32; t++) rel[t] = __cosf(fmaf(dt, freq[t], phs[t]));

  float out[17];
#pragma unroll
  for (int c = 0; c < 17; c++) out[c] = b2[c];

#pragma unroll 3
  for (int j = 0; j < 33; j++) {
    float acc = b1[j];
#pragma unroll
    for (int k = 0; k < 17; k++) acc = fmaf(xi[k], W1[k * 33 + j], acc);
#pragma unroll
    for (int k = 0; k < 17; k++) acc = fmaf(xj[k], W1[(17 + k) * 33 + j], acc);
#pragma unroll
    for (int k = 0; k < 32; k++) acc = fmaf(rel[k], W1[(34 + k) * 33 + j], acc);
    acc = fmaxf(acc, 0.0f);
#pragma unroll
    for (int c = 0; c < 17; c++) out[c] = fmaf(acc, W2[j * 17 + c], out[c]);
  }

#pragma unroll
  for (int c = 0; c < 17; c++) {
    float f = tanh_factor(out[c]);
    atomic_add_f32(&accum[dstn * 17 + c], f * xi[c]);
  }
  atomic_add_f32(&counts[dstn], 1.0f);
}

// ---------------------------------------------------------------------------
// Phase 1 node kernel: h[n] = (x[n] + accum[n]/max(cnt,1)) @ projW + projb.
// Also emits bf16 copy of h for the MFMA edge kernel.
// ---------------------------------------------------------------------------
__global__ __launch_bounds__(256) void phase1_node(
    const float* __restrict__ x, const float* __restrict__ acc1,
    const float* __restrict__ counts, const float* __restrict__ Wp,
    const float* __restrict__ bp, float* __restrict__ h,
    unsigned short* __restrict__ hb, int N)
{
  __shared__ float s0[4][20];
  const int t = threadIdx.x;
  const int nb = blockIdx.x << 2;
  if (t < 68) {
    int nl = t / 17, c = t % 17;
    int n = nb + nl;
    float v = 0.0f;
    if (n < N) {
      float cnt = fmaxf(counts[n], 1.0f);
      v = x[n * 17 + c] + acc1[n * 17 + c] / cnt;
    }
    s0[nl][c] = v;
  }
  __syncthreads();
  int nl = t >> 6, j = t & 63;
  int n = nb + nl;
  if (n < N) {
    float acc = bp[j];
#pragma unroll
    for (int c = 0; c < 17; c++) acc = fmaf(s0[nl][c], Wp[c * 64 + j], acc);
    h[n * 64 + j] = acc;
    hb[n * 64 + j] = f2bf(acc);
  }
}

// ---------------------------------------------------------------------------
// Weight prep: bf16-convert + transpose smp weights.
//   W1t[l][n][k] (n=out col 0..63, k=0..127), W2t[l][n][k] (k=0..63)
// ---------------------------------------------------------------------------
__global__ __launch_bounds__(256) void prep_w(
    const float* __restrict__ sW1, const float* __restrict__ sW2,
    unsigned short* __restrict__ W1t, unsigned short* __restrict__ W2t)
{
  int i = blockIdx.x * 256 + threadIdx.x;
  if (i < 2 * 64 * 128) {
    int l = i >> 13; int r = i & 8191; int n = r >> 7; int k = r & 127;
    W1t[i] = f2bf(sW1[((size_t)l * 128 + k) * 64 + n]);
  }
  if (i < 2 * 64 * 64) {
    int l = i >> 12; int r = i & 4095; int n = r >> 6; int k = r & 63;
    W2t[i] = f2bf(sW2[((size_t)l * 64 + k) * 64 + n]);
  }
}

// ---------------------------------------------------------------------------
// Phase 2 edge kernel (MFMA): 64-edge tiles, 256 threads = 4 waves.
// Wave w owns 16-edge row-block w; loops 4 col-blocks of 16.
// A = [h_dst | h_src] bf16 (64x128), B = Wt bf16 (staged once per block).
// LDS rows padded: 272B / 144B -> bank advance 4/row = 2-way (free, m136).
// ---------------------------------------------------------------------------
__global__ __launch_bounds__(256) void phase2_edge(
    const unsigned short* __restrict__ hb, const int* __restrict__ ei,
    const unsigned short* __restrict__ W1t, const float* __restrict__ b1,
    const unsigned short* __restrict__ W2t, const float* __restrict__ b2,
    float* __restrict__ accum, int E, int ntiles)
{
  __shared__ unsigned short sA[64][136];    // [edge][k0..127]  17408 B
  __shared__ unsigned short sW1t[64][136];  // [n][k0..127]     17408 B
  __shared__ unsigned short sW2t[64][72];   // [n][k0..63]       9216 B
  __shared__ unsigned short sHid[64][72];   // [edge][k0..63]    9216 B
  __shared__ float sb1[64], sb2[64];
  __shared__ int   sDst[64];

  const int t = threadIdx.x;
  const int wv   = t >> 6;
  const int lane = t & 63;
  const int l16  = lane & 15;
  const int quad = lane >> 4;

  // stage weights + biases once per block
#pragma unroll
  for (int i = 0; i < 4; i++) {
    int g = t + i * 256; int r = g >> 4, c = g & 15;
    *(uint4*)&sW1t[r][c * 8] = *(const uint4*)&W1t[r * 128 + c * 8];
  }
#pragma unroll
  for (int i = 0; i < 2; i++) {
    int g = t + i * 256; int r = g >> 3, c = g & 7;
    *(uint4*)&sW2t[r][c * 8] = *(const uint4*)&W2t[r * 64 + c * 8];
  }
  if (t < 64) { sb1[t] = b1[t]; sb2[t] = b2[t]; }
  __syncthreads();

  for (int tile = blockIdx.x; tile < ntiles; tile += gridDim.x) {
    const int eb = tile << 6;

    // stage A: row r = edge eb+r; cols 0..63 = h[dst], 64..127 = h[src]
#pragma unroll
    for (int i = 0; i < 4; i++) {
      int g = t + i * 256; int r = g >> 4, c = g & 15;
      int er = eb + r; if (er >= E) er = E - 1;
      int node = (c >= 8) ? ei[er] : ei[E + er];  // src : dst
      if (c == 0) sDst[r] = node;
      *(uint4*)&sA[r][c * 8] = *(const uint4*)&hb[(size_t)node * 64 + (c & 7) * 8];
    }
    __syncthreads();                               // 1

    // pass 1: hidden(64x64) = relu([h_i|h_j](64x128) @ W1(128x64) + b1)
    f32x4 acc[4];
#pragma unroll
    for (int cb = 0; cb < 4; cb++) {
      float b = sb1[cb * 16 + l16];
      acc[cb] = (f32x4){b, b, b, b};
    }
#pragma unroll
    for (int kb = 0; kb < 4; kb++) {
      s16x8 aF = *(const s16x8*)&sA[wv * 16 + l16][kb * 32 + quad * 8];
#pragma unroll
      for (int cb = 0; cb < 4; cb++) {
        s16x8 bF = *(const s16x8*)&sW1t[cb * 16 + l16][kb * 32 + quad * 8];
        acc[cb] = __builtin_amdgcn_mfma_f32_16x16x32_bf16(aF, bF, acc[cb], 0, 0, 0);
      }
    }
    // relu -> sHid (bf16). D layout: row=quad*4+reg, col=l16 (per 16x16 tile)
#pragma unroll
    for (int cb = 0; cb < 4; cb++)
#pragma unroll
      for (int reg = 0; reg < 4; reg++)
        sHid[wv * 16 + quad * 4 + reg][cb * 16 + l16] = f2bf(fmaxf(acc[cb][reg], 0.0f));
    __syncthreads();                               // 2

    // pass 2: u(64x64) = hidden @ W2 + b2
#pragma unroll
    for (int cb = 0; cb < 4; cb++) {
      float b = sb2[cb * 16 + l16];
      acc[cb] = (f32x4){b, b, b, b};
    }
#pragma unroll
    for (int kb = 0; kb < 2; kb++) {
      s16x8 aF = *(const s16x8*)&sHid[wv * 16 + l16][kb * 32 + quad * 8];
#pragma unroll
      for (int cb = 0; cb < 4; cb++) {
        s16x8 bF = *(const s16x8*)&sW2t[cb * 16 + l16][kb * 32 + quad * 8];
        acc[cb] = __builtin_amdgcn_mfma_f32_16x16x32_bf16(aF, bF, acc[cb], 0, 0, 0);
      }
    }

    // epilogue: msg = (2*tanh(u)-1) * h_i -> atomic scatter to accum[dst]
#pragma unroll
    for (int reg = 0; reg < 4; reg++) {
      int row = wv * 16 + quad * 4 + reg;
      int er = eb + row;
      if (er < E) {
        int dn = sDst[row];
#pragma unroll
        for (int cb = 0; cb < 4; cb++) {
          int col = cb * 16 + l16;
          float f  = tanh_factor(acc[cb][reg]);
          float hi = bf2f(sA[row][col]);
          atomic_add_f32(&accum[(size_t)dn * 64 + col], f * hi);
        }
      }
    }
    __syncthreads();                               // 3: sA/sDst reuse
  }
}

// ---------------------------------------------------------------------------
// Node update + BN statistics (sum, sumsq per column).
// ---------------------------------------------------------------------------
__global__ __launch_bounds__(256) void node_update_bn(
    float* __restrict__ h, const float* __restrict__ accum,
    const float* __restrict__ counts, float* __restrict__ bns,
    float* __restrict__ bnq, int N)
{
  const int t = threadIdx.x;
  float ls = 0.0f, lq = 0.0f;
  int total = N * 64;
  for (int idx = blockIdx.x * 256 + t; idx < total; idx += gridDim.x * 256) {
    int n = idx >> 6;
    float cnt = fmaxf(counts[n], 1.0f);
    float v = h[idx] + accum[idx] / cnt;
    h[idx] = v;
    ls += v; lq += v * v;
  }
  __shared__ float ss[256], sq[256];
  ss[t] = ls; sq[t] = lq;
  __syncthreads();
  if (t < 64) {
    float s = ss[t] + ss[t + 64] + ss[t + 128] + ss[t + 192];
    float q = sq[t] + sq[t + 64] + sq[t + 128] + sq[t + 192];
    atomic_add_f32(&bns[t], s);
    atomic_add_f32(&bnq[t], q);
  }
}

// ---------------------------------------------------------------------------
// BN apply + relu (in place); optional bf16 mirror for next MFMA layer.
// ---------------------------------------------------------------------------
__global__ __launch_bounds__(256) void bn_apply_relu(
    float* __restrict__ d, const float* __restrict__ bns,
    const float* __restrict__ bnq, const float* __restrict__ gam,
    const float* __restrict__ bet, unsigned short* __restrict__ hbOut,
    int total, int cmask, float invRows)
{
  for (int idx = blockIdx.x * 256 + threadIdx.x; idx < total;
       idx += gridDim.x * 256) {
    int c = idx & cmask;
    float m = bns[c] * invRows;
    float var = bnq[c] * invRows - m * m;
    float sc = gam[c] * rsqrtf(var + 1e-5f);
    float v = fmaxf((d[idx] - m) * sc + bet[c], 0.0f);
    d[idx] = v;
    if (hbOut) hbOut[idx] = f2bf(v);
  }
}

// ---------------------------------------------------------------------------
// Classifier matmul (rows x K @ K x C) + bias, with BN stats.
// ---------------------------------------------------------------------------
__global__ __launch_bounds__(256) void clf_mm_bn(
    const float* __restrict__ in, const float* __restrict__ W,
    const float* __restrict__ b, float* __restrict__ out,
    float* __restrict__ bns, float* __restrict__ bnq,
    int rows, int K, int cshift)
{
  const int t = threadIdx.x;
  const int C = 1 << cshift;
  int total = rows << cshift;
  float ls = 0.0f, lq = 0.0f;
  for (int idx = blockIdx.x * 256 + t; idx < total; idx += gridDim.x * 256) {
    int n = idx >> cshift;
    int c = idx & (C - 1);
    float acc = b[c];
#pragma unroll 8
    for (int k = 0; k < K; k++) acc = fmaf(in[n * K + k], W[(k << cshift) + c], acc);
    out[idx] = acc;
    ls += acc; lq += acc * acc;
  }
  __shared__ float ss[256], sq[256];
  ss[t] = ls; sq[t] = lq;
  __syncthreads();
  if (t < C) {
    float s = 0.0f, q = 0.0f;
    for (int i = t; i < 256; i += C) { s += ss[i]; q += sq[i]; }
    atomic_add_f32(&bns[t], s);
    atomic_add_f32(&bnq[t], q);
  }
}

__global__ __launch_bounds__(256) void clf_final(
    const float* __restrict__ z2, const float* __restrict__ W3,
    const float* __restrict__ b3, float* __restrict__ out, int rows)
{
  int n = blockIdx.x * 256 + threadIdx.x;
  if (n >= rows) return;
  float acc = b3[0];
#pragma unroll
  for (int k = 0; k < 32; k++) acc = fmaf(z2[n * 32 + k], W3[k], acc);
  out[n] = acc;
}

// ---------------------------------------------------------------------------
extern "C" void kernel_launch(void* const* d_in, const int* in_sizes, int n_in,
                              void* d_out, int out_size, void* d_ws, size_t ws_size,
                              hipStream_t stream)
{
  const float* x    = (const float*)d_in[0];
  const int*   ei   = (const int*)  d_in[1];
  const float* dts  = (const float*)d_in[2];
  const float* freq = (const float*)d_in[4];
  const float* phs  = (const float*)d_in[5];
  const float* tW1  = (const float*)d_in[6];
  const float* tb1  = (const float*)d_in[7];
  const float* tW2  = (const float*)d_in[8];
  const float* tb2  = (const float*)d_in[9];
  const float* pW   = (const float*)d_in[10];
  const float* pb   = (const float*)d_in[11];
  const float* sW1  = (const float*)d_in[12];
  const float* sb1  = (const float*)d_in[13];
  const float* sW2  = (const float*)d_in[14];
  const float* sb2  = (const float*)d_in[15];
  const float* bng  = (const float*)d_in[16];
  const float* bnb  = (const float*)d_in[17];
  const float* cW1  = (const float*)d_in[18];
  const float* cb1  = (const float*)d_in[19];
  const float* cg1  = (const float*)d_in[20];
  const float* cbb1 = (const float*)d_in[21];
  const float* cW2  = (const float*)d_in[22];
  const float* cb2  = (const float*)d_in[23];
  const float* cg2  = (const float*)d_in[24];
  const float* cbb2 = (const float*)d_in[25];
  const float* cW3  = (const float*)d_in[26];
  const float* cb3  = (const float*)d_in[27];
  float* out = (float*)d_out;

  const int N = in_sizes[0] / 17;
  const int E = in_sizes[1] / 2;
  const int B = out_size;

  // workspace layout (float slots)
  float* ws     = (float*)d_ws;
  float* h      = ws;                           // N*64
  float* acc2   = h      + (size_t)N * 64;      // N*64
  float* counts = acc2   + (size_t)N * 64;      // N
  float* acc1   = counts + (size_t)N;           // N*17 (reused as z1/z2)
  float* z1     = acc1;                         // B*64
  float* z2     = z1     + (size_t)B * 64;      // B*32
  float* bns    = acc1   + (size_t)N * 17;      // 64
  float* bnq    = bns + 64;                     // 64
  unsigned short* hb  = (unsigned short*)(bnq + 64);     // N*64 bf16 (N*32 slots)
  unsigned short* W1t = hb + (size_t)N * 64;             // 2*64*128 bf16
  unsigned short* W2t = W1t + 2 * 64 * 128;              // 2*64*64 bf16
  size_t needed = ((size_t)N * 64 * 2 + N + (size_t)N * 17 + 128
                   + (size_t)N * 32 + 8192 + 4096) * 4;
  if (ws_size < needed) return;  // fail visibly (output stays poisoned)

  const int ntiles = (E + 63) / 64;

  // phase 1 (+ weight prep in parallel)
  hipMemsetAsync(counts, 0, (size_t)(N + (size_t)N * 17) * 4, stream);
  prep_w<<<64, 256, 0, stream>>>(sW1, sW2, W1t, W2t);
  phase1_edge<<<(E + 255) / 256, 256, 0, stream>>>(
      x, ei, dts, freq, phs, tW1, tb1, tW2, tb2, acc1, counts, E);
  phase1_node<<<(N + 3) / 4, 256, 0, stream>>>(x, acc1, counts, pW, pb, h, hb, N);

  // phase 2: L = 2 message-passing + BN layers
  for (int l = 0; l < 2; l++) {
    hipMemsetAsync(acc2, 0, (size_t)N * 64 * 4, stream);
    hipMemsetAsync(bns, 0, 128 * 4, stream);
    phase2_edge<<<768, 256, 0, stream>>>(
        hb, ei, W1t + (size_t)l * 64 * 128, sb1 + l * 64,
        W2t + (size_t)l * 64 * 64, sb2 + l * 64, acc2, E, ntiles);
    node_update_bn<<<1024, 256, 0, stream>>>(h, acc2, counts, bns, bnq, N);
    bn_apply_relu<<<2048, 256, 0, stream>>>(
        h, bns, bnq, bng + l * 64, bnb + l * 64, hb, N * 64, 63, 1.0f / (float)N);
  }

  // classifier on first B rows of h
  hipMemsetAsync(bns, 0, 128 * 4, stream);
  clf_mm_bn<<<2500, 256, 0, stream>>>(h, cW1, cb1, z1, bns, bnq, B, 64, 6);
  bn_apply_relu<<<1024, 256, 0, stream>>>(z1, bns, bnq, cg1, cbb1, nullptr,
                                          B * 64, 63, 1.0f / (float)B);
  hipMemsetAsync(bns, 0, 128 * 4, stream);
  clf_mm_bn<<<1250, 256, 0, stream>>>(z1, cW2, cb2, z2, bns, bnq, B, 64, 5);
  bn_apply_relu<<<512, 256, 0, stream>>>(z2, bns, bnq, cg2, cbb2, nullptr,
                                         B * 32, 31, 1.0f / (float)B);
  clf_final<<<(B + 255) / 256, 256, 0, stream>>>(z2, cW3, cb3, out, B);
}

// Round 3
// 1411.994 us; speedup vs baseline: 3.9367x; 1.8471x over previous
//
#include <hip/hip_runtime.h>
#include <hip/hip_bf16.h>

// ---------------------------------------------------------------------------
// THEGCNModel — R3:
//   * phase1_edge: LDS-transpose scatter -> lane-consecutive atomics
//     (R2 evidence: 900MB WRITE for 109MB payload = scattered-atomic bound).
//   * identity: segment_mean((2p-1)*x_i) = x[dst] * mean(2p-1) -> scatter only
//     the factor f; node update becomes h = x*(1+acc/cnt). Same for phase2.
// ---------------------------------------------------------------------------

typedef float  f32x4 __attribute__((ext_vector_type(4)));
typedef short  s16x8 __attribute__((ext_vector_type(8)));

__device__ __forceinline__ float tanh_factor(float u) {
  // 2*tanh(u) - 1 == 1 - 4/(exp(2u)+1)
  float e = __expf(2.0f * u);
  return 1.0f - 4.0f / (e + 1.0f);
}

__device__ __forceinline__ void atomic_add_f32(float* p, float v) {
  unsafeAtomicAdd(p, v);  // native global_atomic_add_f32 on gfx950
}

__device__ __forceinline__ unsigned short f2bf(float f) {
  __hip_bfloat16 b = __float2bfloat16(f);
  return *(unsigned short*)&b;
}

// ---------------------------------------------------------------------------
// Phase 1 edge kernel: 256 edges/block, per-thread MLP, coalesced LDS-staged
// atomic scatter of the 17 factors per edge.
// ---------------------------------------------------------------------------
__global__ __launch_bounds__(256) void phase1_edge(
    const float* __restrict__ x, const int* __restrict__ ei,
    const float* __restrict__ dts, const float* __restrict__ freq,
    const float* __restrict__ phs,
    const float* __restrict__ W1, const float* __restrict__ b1,
    const float* __restrict__ W2, const float* __restrict__ b2,
    float* __restrict__ accum, float* __restrict__ counts, int E)
{
  __shared__ float sF[256 * 17];   // flat [edge_local*17 + c]
  __shared__ int   sDst[256];

  const int t = threadIdx.x;
  const int e = blockIdx.x * 256 + t;
  int dstn = 0;

  if (e < E) {
    int srcn = ei[e];
    dstn = ei[E + e];

    float xi[17], xj[17];
#pragma unroll
    for (int c = 0; c < 17; c++) { xi[c] = x[dstn * 17 + c]; xj[c] = x[srcn * 17 + c]; }

    float dt = dts[e];
    float rel[32];
#pragma unroll
    for (int k = 0; k < 32; k++) rel[k] = __cosf(fmaf(dt, freq[k], phs[k]));

    float out[17];
#pragma unroll
    for (int c = 0; c < 17; c++) out[c] = b2[c];

#pragma unroll 3
    for (int j = 0; j < 33; j++) {
      float acc = b1[j];
#pragma unroll
      for (int k = 0; k < 17; k++) acc = fmaf(xi[k], W1[k * 33 + j], acc);
#pragma unroll
      for (int k = 0; k < 17; k++) acc = fmaf(xj[k], W1[(17 + k) * 33 + j], acc);
#pragma unroll
      for (int k = 0; k < 32; k++) acc = fmaf(rel[k], W1[(34 + k) * 33 + j], acc);
      acc = fmaxf(acc, 0.0f);
#pragma unroll
      for (int c = 0; c < 17; c++) out[c] = fmaf(acc, W2[j * 17 + c], out[c]);
    }

#pragma unroll
    for (int c = 0; c < 17; c++) sF[t * 17 + c] = tanh_factor(out[c]);
    atomic_add_f32(&counts[dstn], 1.0f);
  } else {
#pragma unroll
    for (int c = 0; c < 17; c++) sF[t * 17 + c] = 0.0f;  // adds 0 to row 0
  }
  sDst[t] = dstn;
  __syncthreads();

  // coalesced scatter: idx = eL*17 + c, consecutive lanes -> consecutive addrs
#pragma unroll
  for (int k = 0; k < 17; k++) {
    int idx = t + k * 256;
    int eL = idx / 17;
    int c = idx - eL * 17;
    atomic_add_f32(&accum[(size_t)sDst[eL] * 17 + c], sF[idx]);
  }
}

// ---------------------------------------------------------------------------
// Phase 1 node kernel: h[n] = (x[n] * (1 + acc/max(cnt,1))) @ projW + projb.
// ---------------------------------------------------------------------------
__global__ __launch_bounds__(256) void phase1_node(
    const float* __restrict__ x, const float* __restrict__ acc1,
    const float* __restrict__ counts, const float* __restrict__ Wp,
    const float* __restrict__ bp, float* __restrict__ h,
    unsigned short* __restrict__ hb, int N)
{
  __shared__ float s0[4][20];
  const int t = threadIdx.x;
  const int nb = blockIdx.x << 2;
  if (t < 68) {
    int nl = t / 17, c = t % 17;
    int n = nb + nl;
    float v = 0.0f;
    if (n < N) {
      float cnt = fmaxf(counts[n], 1.0f);
      v = x[n * 17 + c] * (1.0f + acc1[n * 17 + c] / cnt);
    }
    s0[nl][c] = v;
  }
  __syncthreads();
  int nl = t >> 6, j = t & 63;
  int n = nb + nl;
  if (n < N) {
    float acc = bp[j];
#pragma unroll
    for (int c = 0; c < 17; c++) acc = fmaf(s0[nl][c], Wp[c * 64 + j], acc);
    h[n * 64 + j] = acc;
    hb[n * 64 + j] = f2bf(acc);
  }
}

// ---------------------------------------------------------------------------
// Weight prep: bf16-convert + transpose smp weights.
// ---------------------------------------------------------------------------
__global__ __launch_bounds__(256) void prep_w(
    const float* __restrict__ sW1, const float* __restrict__ sW2,
    unsigned short* __restrict__ W1t, unsigned short* __restrict__ W2t)
{
  int i = blockIdx.x * 256 + threadIdx.x;
  if (i < 2 * 64 * 128) {
    int l = i >> 13; int r = i & 8191; int n = r >> 7; int k = r & 127;
    W1t[i] = f2bf(sW1[((size_t)l * 128 + k) * 64 + n]);
  }
  if (i < 2 * 64 * 64) {
    int l = i >> 12; int r = i & 4095; int n = r >> 6; int k = r & 63;
    W2t[i] = f2bf(sW2[((size_t)l * 64 + k) * 64 + n]);
  }
}

// ---------------------------------------------------------------------------
// Phase 2 edge kernel (MFMA): 64-edge tiles, 256 threads = 4 waves.
// Epilogue scatters only f = 2*tanh(u)-1 (identity moved *h_i to node side).
// ---------------------------------------------------------------------------
__global__ __launch_bounds__(256) void phase2_edge(
    const unsigned short* __restrict__ hb, const int* __restrict__ ei,
    const unsigned short* __restrict__ W1t, const float* __restrict__ b1,
    const unsigned short* __restrict__ W2t, const float* __restrict__ b2,
    float* __restrict__ accum, int E, int ntiles)
{
  __shared__ unsigned short sA[64][136];    // [edge][k0..127]
  __shared__ unsigned short sW1t[64][136];  // [n][k0..127]
  __shared__ unsigned short sW2t[64][72];   // [n][k0..63]
  __shared__ unsigned short sHid[64][72];   // [edge][k0..63]
  __shared__ float sb1[64], sb2[64];
  __shared__ int   sDst[64];

  const int t = threadIdx.x;
  const int wv   = t >> 6;
  const int lane = t & 63;
  const int l16  = lane & 15;
  const int quad = lane >> 4;

#pragma unroll
  for (int i = 0; i < 4; i++) {
    int g = t + i * 256; int r = g >> 4, c = g & 15;
    *(uint4*)&sW1t[r][c * 8] = *(const uint4*)&W1t[r * 128 + c * 8];
  }
#pragma unroll
  for (int i = 0; i < 2; i++) {
    int g = t + i * 256; int r = g >> 3, c = g & 7;
    *(uint4*)&sW2t[r][c * 8] = *(const uint4*)&W2t[r * 64 + c * 8];
  }
  if (t < 64) { sb1[t] = b1[t]; sb2[t] = b2[t]; }
  __syncthreads();

  for (int tile = blockIdx.x; tile < ntiles; tile += gridDim.x) {
    const int eb = tile << 6;

#pragma unroll
    for (int i = 0; i < 4; i++) {
      int g = t + i * 256; int r = g >> 4, c = g & 15;
      int er = eb + r; if (er >= E) er = E - 1;
      int node = (c >= 8) ? ei[er] : ei[E + er];  // src : dst
      if (c == 0) sDst[r] = node;
      *(uint4*)&sA[r][c * 8] = *(const uint4*)&hb[(size_t)node * 64 + (c & 7) * 8];
    }
    __syncthreads();                               // 1

    f32x4 acc[4];
#pragma unroll
    for (int cb = 0; cb < 4; cb++) {
      float b = sb1[cb * 16 + l16];
      acc[cb] = (f32x4){b, b, b, b};
    }
#pragma unroll
    for (int kb = 0; kb < 4; kb++) {
      s16x8 aF = *(const s16x8*)&sA[wv * 16 + l16][kb * 32 + quad * 8];
#pragma unroll
      for (int cb = 0; cb < 4; cb++) {
        s16x8 bF = *(const s16x8*)&sW1t[cb * 16 + l16][kb * 32 + quad * 8];
        acc[cb] = __builtin_amdgcn_mfma_f32_16x16x32_bf16(aF, bF, acc[cb], 0, 0, 0);
      }
    }
#pragma unroll
    for (int cb = 0; cb < 4; cb++)
#pragma unroll
      for (int reg = 0; reg < 4; reg++)
        sHid[wv * 16 + quad * 4 + reg][cb * 16 + l16] = f2bf(fmaxf(acc[cb][reg], 0.0f));
    __syncthreads();                               // 2

#pragma unroll
    for (int cb = 0; cb < 4; cb++) {
      float b = sb2[cb * 16 + l16];
      acc[cb] = (f32x4){b, b, b, b};
    }
#pragma unroll
    for (int kb = 0; kb < 2; kb++) {
      s16x8 aF = *(const s16x8*)&sHid[wv * 16 + l16][kb * 32 + quad * 8];
#pragma unroll
      for (int cb = 0; cb < 4; cb++) {
        s16x8 bF = *(const s16x8*)&sW2t[cb * 16 + l16][kb * 32 + quad * 8];
        acc[cb] = __builtin_amdgcn_mfma_f32_16x16x32_bf16(aF, bF, acc[cb], 0, 0, 0);
      }
    }

    // epilogue: scatter f only (16 consecutive lanes per row -> 64B runs)
#pragma unroll
    for (int reg = 0; reg < 4; reg++) {
      int row = wv * 16 + quad * 4 + reg;
      int er = eb + row;
      if (er < E) {
        int dn = sDst[row];
#pragma unroll
        for (int cb = 0; cb < 4; cb++) {
          int col = cb * 16 + l16;
          atomic_add_f32(&accum[(size_t)dn * 64 + col], tanh_factor(acc[cb][reg]));
        }
      }
    }
    __syncthreads();                               // 3: sA/sDst reuse
  }
}

// ---------------------------------------------------------------------------
// Node update + BN statistics: h = h * (1 + acc/cnt); accumulate sum/sumsq.
// ---------------------------------------------------------------------------
__global__ __launch_bounds__(256) void node_update_bn(
    float* __restrict__ h, const float* __restrict__ accum,
    const float* __restrict__ counts, float* __restrict__ bns,
    float* __restrict__ bnq, int N)
{
  const int t = threadIdx.x;
  float ls = 0.0f, lq = 0.0f;
  int total = N * 64;
  for (int idx = blockIdx.x * 256 + t; idx < total; idx += gridDim.x * 256) {
    int n = idx >> 6;
    float cnt = fmaxf(counts[n], 1.0f);
    float v = h[idx] * (1.0f + accum[idx] / cnt);
    h[idx] = v;
    ls += v; lq += v * v;
  }
  __shared__ float ss[256], sq[256];
  ss[t] = ls; sq[t] = lq;
  __syncthreads();
  if (t < 64) {
    float s = ss[t] + ss[t + 64] + ss[t + 128] + ss[t + 192];
    float q = sq[t] + sq[t + 64] + sq[t + 128] + sq[t + 192];
    atomic_add_f32(&bns[t], s);
    atomic_add_f32(&bnq[t], q);
  }
}

// ---------------------------------------------------------------------------
// BN apply + relu (in place); optional bf16 mirror for next MFMA layer.
// ---------------------------------------------------------------------------
__global__ __launch_bounds__(256) void bn_apply_relu(
    float* __restrict__ d, const float* __restrict__ bns,
    const float* __restrict__ bnq, const float* __restrict__ gam,
    const float* __restrict__ bet, unsigned short* __restrict__ hbOut,
    int total, int cmask, float invRows)
{
  for (int idx = blockIdx.x * 256 + threadIdx.x; idx < total;
       idx += gridDim.x * 256) {
    int c = idx & cmask;
    float m = bns[c] * invRows;
    float var = bnq[c] * invRows - m * m;
    float sc = gam[c] * rsqrtf(var + 1e-5f);
    float v = fmaxf((d[idx] - m) * sc + bet[c], 0.0f);
    d[idx] = v;
    if (hbOut) hbOut[idx] = f2bf(v);
  }
}

// ---------------------------------------------------------------------------
// Classifier matmul (rows x K @ K x C) + bias, with BN stats.
// ---------------------------------------------------------------------------
__global__ __launch_bounds__(256) void clf_mm_bn(
    const float* __restrict__ in, const float* __restrict__ W,
    const float* __restrict__ b, float* __restrict__ out,
    float* __restrict__ bns, float* __restrict__ bnq,
    int rows, int K, int cshift)
{
  const int t = threadIdx.x;
  const int C = 1 << cshift;
  int total = rows << cshift;
  float ls = 0.0f, lq = 0.0f;
  for (int idx = blockIdx.x * 256 + t; idx < total; idx += gridDim.x * 256) {
    int n = idx >> cshift;
    int c = idx & (C - 1);
    float acc = b[c];
#pragma unroll 8
    for (int k = 0; k < K; k++) acc = fmaf(in[n * K + k], W[(k << cshift) + c], acc);
    out[idx] = acc;
    ls += acc; lq += acc * acc;
  }
  __shared__ float ss[256], sq[256];
  ss[t] = ls; sq[t] = lq;
  __syncthreads();
  if (t < C) {
    float s = 0.0f, q = 0.0f;
    for (int i = t; i < 256; i += C) { s += ss[i]; q += sq[i]; }
    atomic_add_f32(&bns[t], s);
    atomic_add_f32(&bnq[t], q);
  }
}

__global__ __launch_bounds__(256) void clf_final(
    const float* __restrict__ z2, const float* __restrict__ W3,
    const float* __restrict__ b3, float* __restrict__ out, int rows)
{
  int n = blockIdx.x * 256 + threadIdx.x;
  if (n >= rows) return;
  float acc = b3[0];
#pragma unroll
  for (int k = 0; k < 32; k++) acc = fmaf(z2[n * 32 + k], W3[k], acc);
  out[n] = acc;
}

// ---------------------------------------------------------------------------
extern "C" void kernel_launch(void* const* d_in, const int* in_sizes, int n_in,
                              void* d_out, int out_size, void* d_ws, size_t ws_size,
                              hipStream_t stream)
{
  const float* x    = (const float*)d_in[0];
  const int*   ei   = (const int*)  d_in[1];
  const float* dts  = (const float*)d_in[2];
  const float* freq = (const float*)d_in[4];
  const float* phs  = (const float*)d_in[5];
  const float* tW1  = (const float*)d_in[6];
  const float* tb1  = (const float*)d_in[7];
  const float* tW2  = (const float*)d_in[8];
  const float* tb2  = (const float*)d_in[9];
  const float* pW   = (const float*)d_in[10];
  const float* pb   = (const float*)d_in[11];
  const float* sW1  = (const float*)d_in[12];
  const float* sb1  = (const float*)d_in[13];
  const float* sW2  = (const float*)d_in[14];
  const float* sb2  = (const float*)d_in[15];
  const float* bng  = (const float*)d_in[16];
  const float* bnb  = (const float*)d_in[17];
  const float* cW1  = (const float*)d_in[18];
  const float* cb1  = (const float*)d_in[19];
  const float* cg1  = (const float*)d_in[20];
  const float* cbb1 = (const float*)d_in[21];
  const float* cW2  = (const float*)d_in[22];
  const float* cb2  = (const float*)d_in[23];
  const float* cg2  = (const float*)d_in[24];
  const float* cbb2 = (const float*)d_in[25];
  const float* cW3  = (const float*)d_in[26];
  const float* cb3  = (const float*)d_in[27];
  float* out = (float*)d_out;

  const int N = in_sizes[0] / 17;
  const int E = in_sizes[1] / 2;
  const int B = out_size;

  // workspace layout (float slots)
  float* ws     = (float*)d_ws;
  float* h      = ws;                           // N*64
  float* acc2   = h      + (size_t)N * 64;      // N*64
  float* counts = acc2   + (size_t)N * 64;      // N
  float* acc1   = counts + (size_t)N;           // N*17 (reused as z1/z2)
  float* z1     = acc1;                         // B*64
  float* z2     = z1     + (size_t)B * 64;      // B*32
  float* bns    = acc1   + (size_t)N * 17;      // 64
  float* bnq    = bns + 64;                     // 64
  unsigned short* hb  = (unsigned short*)(bnq + 64);     // N*64 bf16
  unsigned short* W1t = hb + (size_t)N * 64;             // 2*64*128 bf16
  unsigned short* W2t = W1t + 2 * 64 * 128;              // 2*64*64 bf16
  size_t needed = ((size_t)N * 64 * 2 + N + (size_t)N * 17 + 128
                   + (size_t)N * 32 + 8192 + 4096) * 4;
  if (ws_size < needed) return;  // fail visibly (output stays poisoned)

  const int ntiles = (E + 63) / 64;

  // phase 1 (+ weight prep)
  hipMemsetAsync(counts, 0, (size_t)(N + (size_t)N * 17) * 4, stream);
  prep_w<<<64, 256, 0, stream>>>(sW1, sW2, W1t, W2t);
  phase1_edge<<<(E + 255) / 256, 256, 0, stream>>>(
      x, ei, dts, freq, phs, tW1, tb1, tW2, tb2, acc1, counts, E);
  phase1_node<<<(N + 3) / 4, 256, 0, stream>>>(x, acc1, counts, pW, pb, h, hb, N);

  // phase 2: L = 2 message-passing + BN layers
  for (int l = 0; l < 2; l++) {
    hipMemsetAsync(acc2, 0, (size_t)N * 64 * 4, stream);
    hipMemsetAsync(bns, 0, 128 * 4, stream);
    phase2_edge<<<768, 256, 0, stream>>>(
        hb, ei, W1t + (size_t)l * 64 * 128, sb1 + l * 64,
        W2t + (size_t)l * 64 * 64, sb2 + l * 64, acc2, E, ntiles);
    node_update_bn<<<1024, 256, 0, stream>>>(h, acc2, counts, bns, bnq, N);
    bn_apply_relu<<<2048, 256, 0, stream>>>(
        h, bns, bnq, bng + l * 64, bnb + l * 64, hb, N * 64, 63, 1.0f / (float)N);
  }

  // classifier on first B rows of h
  hipMemsetAsync(bns, 0, 128 * 4, stream);
  clf_mm_bn<<<2500, 256, 0, stream>>>(h, cW1, cb1, z1, bns, bnq, B, 64, 6);
  bn_apply_relu<<<1024, 256, 0, stream>>>(z1, bns, bnq, cg1, cbb1, nullptr,
                                          B * 64, 63, 1.0f / (float)B);
  hipMemsetAsync(bns, 0, 128 * 4, stream);
  clf_mm_bn<<<1250, 256, 0, stream>>>(z1, cW2, cb2, z2, bns, bnq, B, 64, 5);
  bn_apply_relu<<<512, 256, 0, stream>>>(z2, bns, bnq, cg2, cbb2, nullptr,
                                         B * 32, 31, 1.0f / (float)B);
  clf_final<<<(B + 255) / 256, 256, 0, stream>>>(z2, cW3, cb3, out, B);
}

// Round 4
// 1248.846 us; speedup vs baseline: 4.4510x; 1.1306x over previous
//
#include <hip/hip_runtime.h>
#include <hip/hip_bf16.h>

// ---------------------------------------------------------------------------
// THEGCNModel — R4: counting-sort edges by dst once; all edge passes consume
// sorted (dstS, srcS, dtsS). Segmented run-reduction in LDS before atomics
// (R3 evidence: phase2_edge atomic-dword-rate bound, WRITE=400MB @1.04TB/s).
// ---------------------------------------------------------------------------

typedef float  f32x4 __attribute__((ext_vector_type(4)));
typedef short  s16x8 __attribute__((ext_vector_type(8)));

__device__ __forceinline__ float tanh_factor(float u) {
  float e = __expf(2.0f * u);          // 2*tanh(u)-1 == 1 - 4/(exp(2u)+1)
  return 1.0f - 4.0f / (e + 1.0f);
}

__device__ __forceinline__ void atomic_add_f32(float* p, float v) {
  unsafeAtomicAdd(p, v);               // native global_atomic_add_f32
}

__device__ __forceinline__ unsigned short f2bf(float f) {
  __hip_bfloat16 b = __float2bfloat16(f);
  return *(unsigned short*)&b;
}

// ---------------------------------------------------------------------------
// Counting sort by dst: histogram -> 2-level exclusive scan -> scatter.
// ---------------------------------------------------------------------------
__global__ __launch_bounds__(256) void k_hist(
    const int* __restrict__ ei, int* __restrict__ cntI, int E)
{
  int e = blockIdx.x * 256 + threadIdx.x;
  if (e < E) atomicAdd(&cntI[ei[E + e]], 1);
}

__global__ __launch_bounds__(256) void k_scan_block(
    const int* __restrict__ cntI, int* __restrict__ cursor,
    int* __restrict__ bsum, int N)
{
  __shared__ int s[256];
  const int t = threadIdx.x;
  int i = blockIdx.x * 256 + t;
  int v = (i < N) ? cntI[i] : 0;
  s[t] = v;
  for (int off = 1; off < 256; off <<= 1) {
    __syncthreads();
    int x = (t >= off) ? s[t - off] : 0;
    __syncthreads();
    s[t] += x;
  }
  __syncthreads();
  if (i < N) cursor[i] = s[t] - v;          // local exclusive
  if (t == 255) bsum[blockIdx.x] = s[255];
}

__global__ __launch_bounds__(512) void k_scan_bsum(int* __restrict__ bsum, int nb)
{
  __shared__ int s[512];
  const int t = threadIdx.x;
  int v = (t < nb) ? bsum[t] : 0;
  s[t] = v;
  for (int off = 1; off < 512; off <<= 1) {
    __syncthreads();
    int x = (t >= off) ? s[t - off] : 0;
    __syncthreads();
    s[t] += x;
  }
  __syncthreads();
  if (t < nb) bsum[t] = s[t] - v;           // exclusive
}

__global__ __launch_bounds__(256) void k_scan_add(
    int* __restrict__ cursor, const int* __restrict__ bsum, int N)
{
  int i = blockIdx.x * 256 + threadIdx.x;
  if (i < N) cursor[i] += bsum[blockIdx.x];
}

__global__ __launch_bounds__(256) void k_scatter(
    const int* __restrict__ ei, const float* __restrict__ dts,
    int* __restrict__ cursor, int* __restrict__ dstS,
    int* __restrict__ srcS, float* __restrict__ dtsS, int E)
{
  int e = blockIdx.x * 256 + threadIdx.x;
  if (e >= E) return;
  int d = ei[E + e];
  int pos = atomicAdd(&cursor[d], 1);
  dstS[pos] = d;
  srcS[pos] = ei[e];
  dtsS[pos] = dts[e];
}

// ---------------------------------------------------------------------------
// Phase 1 edge kernel: sorted edges, per-thread MLP, LDS segmented reduction
// of the 17 factors per dst-run, then atomics (one per run per col).
// ---------------------------------------------------------------------------
__global__ __launch_bounds__(256) void phase1_edge(
    const float* __restrict__ x, const int* __restrict__ dstS,
    const int* __restrict__ srcS, const float* __restrict__ dtsS,
    const float* __restrict__ freq, const float* __restrict__ phs,
    const float* __restrict__ W1, const float* __restrict__ b1,
    const float* __restrict__ W2, const float* __restrict__ b2,
    float* __restrict__ accum, int E)
{
  __shared__ float sF[256 * 17];
  __shared__ int   sDst[256];

  const int t = threadIdx.x;
  const int i = blockIdx.x * 256 + t;
  int dstn = 0;

  if (i < E) {
    dstn = dstS[i];
    int srcn = srcS[i];

    float xi[17], xj[17];
#pragma unroll
    for (int c = 0; c < 17; c++) { xi[c] = x[dstn * 17 + c]; xj[c] = x[srcn * 17 + c]; }

    float dt = dtsS[i];
    float rel[32];
#pragma unroll
    for (int k = 0; k < 32; k++) rel[k] = __cosf(fmaf(dt, freq[k], phs[k]));

    float out[17];
#pragma unroll
    for (int c = 0; c < 17; c++) out[c] = b2[c];

#pragma unroll 3
    for (int j = 0; j < 33; j++) {
      float acc = b1[j];
#pragma unroll
      for (int k = 0; k < 17; k++) acc = fmaf(xi[k], W1[k * 33 + j], acc);
#pragma unroll
      for (int k = 0; k < 17; k++) acc = fmaf(xj[k], W1[(17 + k) * 33 + j], acc);
#pragma unroll
      for (int k = 0; k < 32; k++) acc = fmaf(rel[k], W1[(34 + k) * 33 + j], acc);
      acc = fmaxf(acc, 0.0f);
#pragma unroll
      for (int c = 0; c < 17; c++) out[c] = fmaf(acc, W2[j * 17 + c], out[c]);
    }

#pragma unroll
    for (int c = 0; c < 17; c++) sF[t * 17 + c] = tanh_factor(out[c]);
  } else {
#pragma unroll
    for (int c = 0; c < 17; c++) sF[t * 17 + c] = 0.0f;  // adds 0 to node 0
  }
  sDst[t] = dstn;
  __syncthreads();

  // segmented walk: worker (c, rowgroup of 16); 272 workers over 256 threads
  for (int w = t; w < 272; w += 256) {
    int c = w % 17;
    int r0 = (w / 17) * 16;
    float run = 0.0f;
    int cur = sDst[r0];
#pragma unroll
    for (int k = 0; k < 16; k++) {
      int r = r0 + k;
      int d = sDst[r];
      float v = sF[r * 17 + c];
      if (d != cur) {
        atomic_add_f32(&accum[(size_t)cur * 17 + c], run);
        run = 0.0f; cur = d;
      }
      run += v;
    }
    atomic_add_f32(&accum[(size_t)cur * 17 + c], run);
  }
}

// ---------------------------------------------------------------------------
// Phase 1 node kernel: h[n] = (x[n] * (1 + acc/max(cnt,1))) @ projW + projb.
// ---------------------------------------------------------------------------
__global__ __launch_bounds__(256) void phase1_node(
    const float* __restrict__ x, const float* __restrict__ acc1,
    const int* __restrict__ cntI, const float* __restrict__ Wp,
    const float* __restrict__ bp, float* __restrict__ h,
    unsigned short* __restrict__ hb, int N)
{
  __shared__ float s0[4][20];
  const int t = threadIdx.x;
  const int nb = blockIdx.x << 2;
  if (t < 68) {
    int nl = t / 17, c = t % 17;
    int n = nb + nl;
    float v = 0.0f;
    if (n < N) {
      float cnt = fmaxf((float)cntI[n], 1.0f);
      v = x[n * 17 + c] * (1.0f + acc1[n * 17 + c] / cnt);
    }
    s0[nl][c] = v;
  }
  __syncthreads();
  int nl = t >> 6, j = t & 63;
  int n = nb + nl;
  if (n < N) {
    float acc = bp[j];
#pragma unroll
    for (int c = 0; c < 17; c++) acc = fmaf(s0[nl][c], Wp[c * 64 + j], acc);
    h[n * 64 + j] = acc;
    hb[n * 64 + j] = f2bf(acc);
  }
}

// ---------------------------------------------------------------------------
// Weight prep: bf16-convert + transpose smp weights.
// ---------------------------------------------------------------------------
__global__ __launch_bounds__(256) void prep_w(
    const float* __restrict__ sW1, const float* __restrict__ sW2,
    unsigned short* __restrict__ W1t, unsigned short* __restrict__ W2t)
{
  int i = blockIdx.x * 256 + threadIdx.x;
  if (i < 2 * 64 * 128) {
    int l = i >> 13; int r = i & 8191; int n = r >> 7; int k = r & 127;
    W1t[i] = f2bf(sW1[((size_t)l * 128 + k) * 64 + n]);
  }
  if (i < 2 * 64 * 64) {
    int l = i >> 12; int r = i & 4095; int n = r >> 6; int k = r & 63;
    W2t[i] = f2bf(sW2[((size_t)l * 64 + k) * 64 + n]);
  }
}

// ---------------------------------------------------------------------------
// Phase 2 edge kernel (MFMA + segmented reduction):
// 64-edge tiles (sorted by dst), 256 threads = 4 waves.
// Epilogue: f -> sRed (aliases dead sA), wave-uniform run-walk, coalesced
// 256B atomics at run boundaries only.
// ---------------------------------------------------------------------------
__global__ __launch_bounds__(256) void phase2_edge(
    const unsigned short* __restrict__ hb, const int* __restrict__ dstS,
    const int* __restrict__ srcS,
    const unsigned short* __restrict__ W1t, const float* __restrict__ b1,
    const unsigned short* __restrict__ W2t, const float* __restrict__ b2,
    float* __restrict__ accum, int E, int ntiles)
{
  __shared__ unsigned short sA[64][136];    // A-tile; aliased as f32[64][68] later
  __shared__ unsigned short sW1t[64][136];
  __shared__ unsigned short sW2t[64][72];
  __shared__ unsigned short sHid[64][72];
  __shared__ float sb1[64], sb2[64];
  __shared__ int   sDst[64];
  float* sRedF = (float*)&sA[0][0];         // 64 x 68 f32, row stride 68

  const int t = threadIdx.x;
  const int wv   = t >> 6;
  const int lane = t & 63;
  const int l16  = lane & 15;
  const int quad = lane >> 4;

#pragma unroll
  for (int i = 0; i < 4; i++) {
    int g = t + i * 256; int r = g >> 4, c = g & 15;
    *(uint4*)&sW1t[r][c * 8] = *(const uint4*)&W1t[r * 128 + c * 8];
  }
#pragma unroll
  for (int i = 0; i < 2; i++) {
    int g = t + i * 256; int r = g >> 3, c = g & 7;
    *(uint4*)&sW2t[r][c * 8] = *(const uint4*)&W2t[r * 64 + c * 8];
  }
  if (t < 64) { sb1[t] = b1[t]; sb2[t] = b2[t]; }
  __syncthreads();

  for (int tile = blockIdx.x; tile < ntiles; tile += gridDim.x) {
    const int eb = tile << 6;

    // stage A: row r = sorted edge eb+r; cols 0..63 = h[dst], 64..127 = h[src]
#pragma unroll
    for (int i = 0; i < 4; i++) {
      int g = t + i * 256; int r = g >> 4, c = g & 15;
      int er = eb + r; if (er >= E) er = E - 1;
      int node = (c >= 8) ? srcS[er] : dstS[er];
      if (c == 0) sDst[r] = node;
      *(uint4*)&sA[r][c * 8] = *(const uint4*)&hb[(size_t)node * 64 + (c & 7) * 8];
    }
    __syncthreads();                               // 1

    // pass 1: hidden = relu([h_i|h_j] @ W1 + b1)
    f32x4 acc[4];
#pragma unroll
    for (int cb = 0; cb < 4; cb++) {
      float b = sb1[cb * 16 + l16];
      acc[cb] = (f32x4){b, b, b, b};
    }
#pragma unroll
    for (int kb = 0; kb < 4; kb++) {
      s16x8 aF = *(const s16x8*)&sA[wv * 16 + l16][kb * 32 + quad * 8];
#pragma unroll
      for (int cb = 0; cb < 4; cb++) {
        s16x8 bF = *(const s16x8*)&sW1t[cb * 16 + l16][kb * 32 + quad * 8];
        acc[cb] = __builtin_amdgcn_mfma_f32_16x16x32_bf16(aF, bF, acc[cb], 0, 0, 0);
      }
    }
#pragma unroll
    for (int cb = 0; cb < 4; cb++)
#pragma unroll
      for (int reg = 0; reg < 4; reg++)
        sHid[wv * 16 + quad * 4 + reg][cb * 16 + l16] = f2bf(fmaxf(acc[cb][reg], 0.0f));
    __syncthreads();                               // 2 (also: all sA reads done)

    // pass 2: u = hidden @ W2 + b2
#pragma unroll
    for (int cb = 0; cb < 4; cb++) {
      float b = sb2[cb * 16 + l16];
      acc[cb] = (f32x4){b, b, b, b};
    }
#pragma unroll
    for (int kb = 0; kb < 2; kb++) {
      s16x8 aF = *(const s16x8*)&sHid[wv * 16 + l16][kb * 32 + quad * 8];
#pragma unroll
      for (int cb = 0; cb < 4; cb++) {
        s16x8 bF = *(const s16x8*)&sW2t[cb * 16 + l16][kb * 32 + quad * 8];
        acc[cb] = __builtin_amdgcn_mfma_f32_16x16x32_bf16(aF, bF, acc[cb], 0, 0, 0);
      }
    }

    // f = 2*tanh(u)-1 -> sRed (f32, aliases sA; safe after barrier 2)
#pragma unroll
    for (int reg = 0; reg < 4; reg++) {
      int row = wv * 16 + quad * 4 + reg;
      float f = (eb + row < E) ? tanh_factor(acc[reg >> 2 == 0 ? 0 : 0][0]) : 0.0f;
      (void)f;  // placeholder removed below
    }
#pragma unroll
    for (int cb = 0; cb < 4; cb++)
#pragma unroll
      for (int reg = 0; reg < 4; reg++) {
        int row = wv * 16 + quad * 4 + reg;
        float f = (eb + row < E) ? tanh_factor(acc[cb][reg]) : 0.0f;
        sRedF[row * 68 + cb * 16 + l16] = f;
      }
    __syncthreads();                               // 3

    // wave-uniform segmented walk: thread owns col j, rows r0..r0+15
    {
      int j = t & 63;
      int r0 = (t >> 6) * 16;
      float run = 0.0f;
      int cur = sDst[r0];
#pragma unroll
      for (int k = 0; k < 16; k++) {
        int r = r0 + k;
        int d = sDst[r];                 // wave-uniform
        float v = sRedF[r * 68 + j];
        if (d != cur) {                  // wave-uniform branch
          atomic_add_f32(&accum[(size_t)cur * 64 + j], run);
          run = 0.0f; cur = d;
        }
        run += v;
      }
      atomic_add_f32(&accum[(size_t)cur * 64 + j], run);
    }
    __syncthreads();                               // 4: sA/sDst reuse
  }
}

// ---------------------------------------------------------------------------
// Node update + BN statistics: h = h * (1 + acc/cnt); accumulate sum/sumsq.
// ---------------------------------------------------------------------------
__global__ __launch_bounds__(256) void node_update_bn(
    float* __restrict__ h, const float* __restrict__ accum,
    const int* __restrict__ cntI, float* __restrict__ bns,
    float* __restrict__ bnq, int N)
{
  const int t = threadIdx.x;
  float ls = 0.0f, lq = 0.0f;
  int total = N * 64;
  for (int idx = blockIdx.x * 256 + t; idx < total; idx += gridDim.x * 256) {
    int n = idx >> 6;
    float cnt = fmaxf((float)cntI[n], 1.0f);
    float v = h[idx] * (1.0f + accum[idx] / cnt);
    h[idx] = v;
    ls += v; lq += v * v;
  }
  __shared__ float ss[256], sq[256];
  ss[t] = ls; sq[t] = lq;
  __syncthreads();
  if (t < 64) {
    float s = ss[t] + ss[t + 64] + ss[t + 128] + ss[t + 192];
    float q = sq[t] + sq[t + 64] + sq[t + 128] + sq[t + 192];
    atomic_add_f32(&bns[t], s);
    atomic_add_f32(&bnq[t], q);
  }
}

// ---------------------------------------------------------------------------
// BN apply + relu (in place); optional bf16 mirror for next MFMA layer.
// ---------------------------------------------------------------------------
__global__ __launch_bounds__(256) void bn_apply_relu(
    float* __restrict__ d, const float* __restrict__ bns,
    const float* __restrict__ bnq, const float* __restrict__ gam,
    const float* __restrict__ bet, unsigned short* __restrict__ hbOut,
    int total, int cmask, float invRows)
{
  for (int idx = blockIdx.x * 256 + threadIdx.x; idx < total;
       idx += gridDim.x * 256) {
    int c = idx & cmask;
    float m = bns[c] * invRows;
    float var = bnq[c] * invRows - m * m;
    float sc = gam[c] * rsqrtf(var + 1e-5f);
    float v = fmaxf((d[idx] - m) * sc + bet[c], 0.0f);
    d[idx] = v;
    if (hbOut) hbOut[idx] = f2bf(v);
  }
}

// ---------------------------------------------------------------------------
// Classifier matmul (rows x K @ K x C) + bias, with BN stats.
// ---------------------------------------------------------------------------
__global__ __launch_bounds__(256) void clf_mm_bn(
    const float* __restrict__ in, const float* __restrict__ W,
    const float* __restrict__ b, float* __restrict__ out,
    float* __restrict__ bns, float* __restrict__ bnq,
    int rows, int K, int cshift)
{
  const int t = threadIdx.x;
  const int C = 1 << cshift;
  int total = rows << cshift;
  float ls = 0.0f, lq = 0.0f;
  for (int idx = blockIdx.x * 256 + t; idx < total; idx += gridDim.x * 256) {
    int n = idx >> cshift;
    int c = idx & (C - 1);
    float acc = b[c];
#pragma unroll 8
    for (int k = 0; k < K; k++) acc = fmaf(in[n * K + k], W[(k << cshift) + c], acc);
    out[idx] = acc;
    ls += acc; lq += acc * acc;
  }
  __shared__ float ss[256], sq[256];
  ss[t] = ls; sq[t] = lq;
  __syncthreads();
  if (t < C) {
    float s = 0.0f, q = 0.0f;
    for (int i = t; i < 256; i += C) { s += ss[i]; q += sq[i]; }
    atomic_add_f32(&bns[t], s);
    atomic_add_f32(&bnq[t], q);
  }
}

__global__ __launch_bounds__(256) void clf_final(
    const float* __restrict__ z2, const float* __restrict__ W3,
    const float* __restrict__ b3, float* __restrict__ out, int rows)
{
  int n = blockIdx.x * 256 + threadIdx.x;
  if (n >= rows) return;
  float acc = b3[0];
#pragma unroll
  for (int k = 0; k < 32; k++) acc = fmaf(z2[n * 32 + k], W3[k], acc);
  out[n] = acc;
}

// ---------------------------------------------------------------------------
extern "C" void kernel_launch(void* const* d_in, const int* in_sizes, int n_in,
                              void* d_out, int out_size, void* d_ws, size_t ws_size,
                              hipStream_t stream)
{
  const float* x    = (const float*)d_in[0];
  const int*   ei   = (const int*)  d_in[1];
  const float* dts  = (const float*)d_in[2];
  const float* freq = (const float*)d_in[4];
  const float* phs  = (const float*)d_in[5];
  const float* tW1  = (const float*)d_in[6];
  const float* tb1  = (const float*)d_in[7];
  const float* tW2  = (const float*)d_in[8];
  const float* tb2  = (const float*)d_in[9];
  const float* pW   = (const float*)d_in[10];
  const float* pb   = (const float*)d_in[11];
  const float* sW1  = (const float*)d_in[12];
  const float* sb1  = (const float*)d_in[13];
  const float* sW2  = (const float*)d_in[14];
  const float* sb2  = (const float*)d_in[15];
  const float* bng  = (const float*)d_in[16];
  const float* bnb  = (const float*)d_in[17];
  const float* cW1  = (const float*)d_in[18];
  const float* cb1  = (const float*)d_in[19];
  const float* cg1  = (const float*)d_in[20];
  const float* cbb1 = (const float*)d_in[21];
  const float* cW2  = (const float*)d_in[22];
  const float* cb2  = (const float*)d_in[23];
  const float* cg2  = (const float*)d_in[24];
  const float* cbb2 = (const float*)d_in[25];
  const float* cW3  = (const float*)d_in[26];
  const float* cb3  = (const float*)d_in[27];
  float* out = (float*)d_out;

  const int N = in_sizes[0] / 17;
  const int E = in_sizes[1] / 2;
  const int B = out_size;

  // workspace layout
  float* ws     = (float*)d_ws;
  float* h      = ws;                            // N*64
  float* acc2   = h    + (size_t)N * 64;         // N*64
  float* acc1   = acc2 + (size_t)N * 64;         // N*17 (z1/z2 alias)
  float* z1     = acc1;
  float* z2     = z1 + (size_t)B * 64;
  float* bns    = acc1 + (size_t)N * 17;         // 64
  float* bnq    = bns + 64;                      // 64
  unsigned short* hb  = (unsigned short*)(bnq + 64);   // N*64 bf16
  unsigned short* W1t = hb + (size_t)N * 64;           // 2*64*128
  unsigned short* W2t = W1t + 2 * 64 * 128;            // 2*64*64
  int*   cntI   = (int*)(W2t + 2 * 64 * 64);     // N
  int*   cursor = cntI + N;                      // N
  int*   bsum   = cursor + N;                    // 512
  int*   dstS   = bsum + 512;                    // E
  int*   srcS   = dstS + (size_t)E;              // E
  float* dtsS   = (float*)(srcS + (size_t)E);    // E
  size_t needed = (size_t)((char*)(dtsS + E) - (char*)d_ws);
  if (ws_size < needed) return;  // fail visibly (output stays poisoned)

  const int ntiles = (E + 63) / 64;
  const int NB = (N + 255) / 256;
  if (NB > 512) return;

  // ---- counting sort by dst (also yields counts) ----
  hipMemsetAsync(cntI, 0, (size_t)N * 4, stream);
  hipMemsetAsync(acc1, 0, (size_t)N * 17 * 4, stream);
  k_hist<<<(E + 255) / 256, 256, 0, stream>>>(ei, cntI, E);
  k_scan_block<<<NB, 256, 0, stream>>>(cntI, cursor, bsum, N);
  k_scan_bsum<<<1, 512, 0, stream>>>(bsum, NB);
  k_scan_add<<<NB, 256, 0, stream>>>(cursor, bsum, N);
  k_scatter<<<(E + 255) / 256, 256, 0, stream>>>(ei, dts, cursor, dstS, srcS, dtsS, E);
  prep_w<<<64, 256, 0, stream>>>(sW1, sW2, W1t, W2t);

  // ---- phase 1 ----
  phase1_edge<<<(E + 255) / 256, 256, 0, stream>>>(
      x, dstS, srcS, dtsS, freq, phs, tW1, tb1, tW2, tb2, acc1, E);
  phase1_node<<<(N + 3) / 4, 256, 0, stream>>>(x, acc1, cntI, pW, pb, h, hb, N);

  // ---- phase 2: L = 2 message-passing + BN layers ----
  for (int l = 0; l < 2; l++) {
    hipMemsetAsync(acc2, 0, (size_t)N * 64 * 4, stream);
    hipMemsetAsync(bns, 0, 128 * 4, stream);
    phase2_edge<<<768, 256, 0, stream>>>(
        hb, dstS, srcS, W1t + (size_t)l * 64 * 128, sb1 + l * 64,
        W2t + (size_t)l * 64 * 64, sb2 + l * 64, acc2, E, ntiles);
    node_update_bn<<<1024, 256, 0, stream>>>(h, acc2, cntI, bns, bnq, N);
    bn_apply_relu<<<2048, 256, 0, stream>>>(
        h, bns, bnq, bng + l * 64, bnb + l * 64, hb, N * 64, 63, 1.0f / (float)N);
  }

  // ---- classifier on first B rows of h ----
  hipMemsetAsync(bns, 0, 128 * 4, stream);
  clf_mm_bn<<<2500, 256, 0, stream>>>(h, cW1, cb1, z1, bns, bnq, B, 64, 6);
  bn_apply_relu<<<1024, 256, 0, stream>>>(z1, bns, bnq, cg1, cbb1, nullptr,
                                          B * 64, 63, 1.0f / (float)B);
  hipMemsetAsync(bns, 0, 128 * 4, stream);
  clf_mm_bn<<<1250, 256, 0, stream>>>(z1, cW2, cb2, z2, bns, bnq, B, 64, 5);
  bn_apply_relu<<<512, 256, 0, stream>>>(z2, bns, bnq, cg2, cbb2, nullptr,
                                         B * 32, 31, 1.0f / (float)B);
  clf_final<<<(B + 255) / 256, 256, 0, stream>>>(z2, cW3, cb3, out, B);
}

// Round 5
// 1056.312 us; speedup vs baseline: 5.2623x; 1.1823x over previous
//
#include <hip/hip_runtime.h>
#include <hip/hip_bf16.h>

// ---------------------------------------------------------------------------
// THEGCNModel — R5: phase2_edge weight fragments moved LDS -> registers
// (R4 evidence: latency-bound, 30 ds_read_b128/thread/tile of which 24 were
// loop-invariant weight reads; LDS 54.3KB capped occupancy at 2 blocks/CU).
// LDS now ~27.4KB, VGPR ~160 w/ __launch_bounds__(256,3) -> 3 blocks/CU.
// ---------------------------------------------------------------------------

typedef float  f32x4 __attribute__((ext_vector_type(4)));
typedef short  s16x8 __attribute__((ext_vector_type(8)));

__device__ __forceinline__ float tanh_factor(float u) {
  float e = __expf(2.0f * u);          // 2*tanh(u)-1 == 1 - 4/(exp(2u)+1)
  return 1.0f - 4.0f / (e + 1.0f);
}

__device__ __forceinline__ void atomic_add_f32(float* p, float v) {
  unsafeAtomicAdd(p, v);               // native global_atomic_add_f32
}

__device__ __forceinline__ unsigned short f2bf(float f) {
  __hip_bfloat16 b = __float2bfloat16(f);
  return *(unsigned short*)&b;
}

// ---------------------------------------------------------------------------
// Counting sort by dst: histogram -> 2-level exclusive scan -> scatter.
// ---------------------------------------------------------------------------
__global__ __launch_bounds__(256) void k_hist(
    const int* __restrict__ ei, int* __restrict__ cntI, int E)
{
  int e = blockIdx.x * 256 + threadIdx.x;
  if (e < E) atomicAdd(&cntI[ei[E + e]], 1);
}

__global__ __launch_bounds__(256) void k_scan_block(
    const int* __restrict__ cntI, int* __restrict__ cursor,
    int* __restrict__ bsum, int N)
{
  __shared__ int s[256];
  const int t = threadIdx.x;
  int i = blockIdx.x * 256 + t;
  int v = (i < N) ? cntI[i] : 0;
  s[t] = v;
  for (int off = 1; off < 256; off <<= 1) {
    __syncthreads();
    int x = (t >= off) ? s[t - off] : 0;
    __syncthreads();
    s[t] += x;
  }
  __syncthreads();
  if (i < N) cursor[i] = s[t] - v;          // local exclusive
  if (t == 255) bsum[blockIdx.x] = s[255];
}

__global__ __launch_bounds__(512) void k_scan_bsum(int* __restrict__ bsum, int nb)
{
  __shared__ int s[512];
  const int t = threadIdx.x;
  int v = (t < nb) ? bsum[t] : 0;
  s[t] = v;
  for (int off = 1; off < 512; off <<= 1) {
    __syncthreads();
    int x = (t >= off) ? s[t - off] : 0;
    __syncthreads();
    s[t] += x;
  }
  __syncthreads();
  if (t < nb) bsum[t] = s[t] - v;           // exclusive
}

__global__ __launch_bounds__(256) void k_scan_add(
    int* __restrict__ cursor, const int* __restrict__ bsum, int N)
{
  int i = blockIdx.x * 256 + threadIdx.x;
  if (i < N) cursor[i] += bsum[blockIdx.x];
}

__global__ __launch_bounds__(256) void k_scatter(
    const int* __restrict__ ei, const float* __restrict__ dts,
    int* __restrict__ cursor, int* __restrict__ dstS,
    int* __restrict__ srcS, float* __restrict__ dtsS, int E)
{
  int e = blockIdx.x * 256 + threadIdx.x;
  if (e >= E) return;
  int d = ei[E + e];
  int pos = atomicAdd(&cursor[d], 1);
  dstS[pos] = d;
  srcS[pos] = ei[e];
  dtsS[pos] = dts[e];
}

// ---------------------------------------------------------------------------
// Phase 1 edge kernel: sorted edges, per-thread MLP, LDS segmented reduction
// of the 17 factors per dst-run, then atomics (one per run per col).
// ---------------------------------------------------------------------------
__global__ __launch_bounds__(256) void phase1_edge(
    const float* __restrict__ x, const int* __restrict__ dstS,
    const int* __restrict__ srcS, const float* __restrict__ dtsS,
    const float* __restrict__ freq, const float* __restrict__ phs,
    const float* __restrict__ W1, const float* __restrict__ b1,
    const float* __restrict__ W2, const float* __restrict__ b2,
    float* __restrict__ accum, int E)
{
  __shared__ float sF[256 * 17];
  __shared__ int   sDst[256];

  const int t = threadIdx.x;
  const int i = blockIdx.x * 256 + t;
  int dstn = 0;

  if (i < E) {
    dstn = dstS[i];
    int srcn = srcS[i];

    float xi[17], xj[17];
#pragma unroll
    for (int c = 0; c < 17; c++) { xi[c] = x[dstn * 17 + c]; xj[c] = x[srcn * 17 + c]; }

    float dt = dtsS[i];
    float rel[32];
#pragma unroll
    for (int k = 0; k < 32; k++) rel[k] = __cosf(fmaf(dt, freq[k], phs[k]));

    float out[17];
#pragma unroll
    for (int c = 0; c < 17; c++) out[c] = b2[c];

#pragma unroll 3
    for (int j = 0; j < 33; j++) {
      float acc = b1[j];
#pragma unroll
      for (int k = 0; k < 17; k++) acc = fmaf(xi[k], W1[k * 33 + j], acc);
#pragma unroll
      for (int k = 0; k < 17; k++) acc = fmaf(xj[k], W1[(17 + k) * 33 + j], acc);
#pragma unroll
      for (int k = 0; k < 32; k++) acc = fmaf(rel[k], W1[(34 + k) * 33 + j], acc);
      acc = fmaxf(acc, 0.0f);
#pragma unroll
      for (int c = 0; c < 17; c++) out[c] = fmaf(acc, W2[j * 17 + c], out[c]);
    }

#pragma unroll
    for (int c = 0; c < 17; c++) sF[t * 17 + c] = tanh_factor(out[c]);
  } else {
#pragma unroll
    for (int c = 0; c < 17; c++) sF[t * 17 + c] = 0.0f;  // adds 0 to node 0
  }
  sDst[t] = dstn;
  __syncthreads();

  // segmented walk: worker (c, rowgroup of 16); 272 workers over 256 threads
  for (int w = t; w < 272; w += 256) {
    int c = w % 17;
    int r0 = (w / 17) * 16;
    float run = 0.0f;
    int cur = sDst[r0];
#pragma unroll
    for (int k = 0; k < 16; k++) {
      int r = r0 + k;
      int d = sDst[r];
      float v = sF[r * 17 + c];
      if (d != cur) {
        atomic_add_f32(&accum[(size_t)cur * 17 + c], run);
        run = 0.0f; cur = d;
      }
      run += v;
    }
    atomic_add_f32(&accum[(size_t)cur * 17 + c], run);
  }
}

// ---------------------------------------------------------------------------
// Phase 1 node kernel: h[n] = (x[n] * (1 + acc/max(cnt,1))) @ projW + projb.
// ---------------------------------------------------------------------------
__global__ __launch_bounds__(256) void phase1_node(
    const float* __restrict__ x, const float* __restrict__ acc1,
    const int* __restrict__ cntI, const float* __restrict__ Wp,
    const float* __restrict__ bp, float* __restrict__ h,
    unsigned short* __restrict__ hb, int N)
{
  __shared__ float s0[4][20];
  const int t = threadIdx.x;
  const int nb = blockIdx.x << 2;
  if (t < 68) {
    int nl = t / 17, c = t % 17;
    int n = nb + nl;
    float v = 0.0f;
    if (n < N) {
      float cnt = fmaxf((float)cntI[n], 1.0f);
      v = x[n * 17 + c] * (1.0f + acc1[n * 17 + c] / cnt);
    }
    s0[nl][c] = v;
  }
  __syncthreads();
  int nl = t >> 6, j = t & 63;
  int n = nb + nl;
  if (n < N) {
    float acc = bp[j];
#pragma unroll
    for (int c = 0; c < 17; c++) acc = fmaf(s0[nl][c], Wp[c * 64 + j], acc);
    h[n * 64 + j] = acc;
    hb[n * 64 + j] = f2bf(acc);
  }
}

// ---------------------------------------------------------------------------
// Weight prep: bf16-convert + transpose smp weights.
// ---------------------------------------------------------------------------
__global__ __launch_bounds__(256) void prep_w(
    const float* __restrict__ sW1, const float* __restrict__ sW2,
    unsigned short* __restrict__ W1t, unsigned short* __restrict__ W2t)
{
  int i = blockIdx.x * 256 + threadIdx.x;
  if (i < 2 * 64 * 128) {
    int l = i >> 13; int r = i & 8191; int n = r >> 7; int k = r & 127;
    W1t[i] = f2bf(sW1[((size_t)l * 128 + k) * 64 + n]);
  }
  if (i < 2 * 64 * 64) {
    int l = i >> 12; int r = i & 4095; int n = r >> 6; int k = r & 63;
    W2t[i] = f2bf(sW2[((size_t)l * 64 + k) * 64 + n]);
  }
}

// ---------------------------------------------------------------------------
// Phase 2 edge kernel (MFMA, weights in registers):
// 64-edge tiles (sorted by dst), 256 threads = 4 waves.
// B-fragments (W1: 16 s16x8, W2: 8 s16x8 = 96 VGPR) + biases loaded once.
// LDS: sA(17408) + sHid(9216) + sDst(256) = ~27KB -> 3 blocks/CU w/ VGPR<=170.
// ---------------------------------------------------------------------------
__global__ __launch_bounds__(256, 3) void phase2_edge(
    const unsigned short* __restrict__ hb, const int* __restrict__ dstS,
    const int* __restrict__ srcS,
    const unsigned short* __restrict__ W1t, const float* __restrict__ b1,
    const unsigned short* __restrict__ W2t, const float* __restrict__ b2,
    float* __restrict__ accum, int E, int ntiles)
{
  __shared__ unsigned short sA[64][136];    // A-tile; aliased as f32[64][68] later
  __shared__ unsigned short sHid[64][72];
  __shared__ int   sDst[64];
  float* sRedF = (float*)&sA[0][0];         // 64 x 68 f32

  const int t = threadIdx.x;
  const int wv   = t >> 6;
  const int lane = t & 63;
  const int l16  = lane & 15;
  const int quad = lane >> 4;

  // loop-invariant weight fragments + biases -> registers
  s16x8 w1f[4][4], w2f[4][2];
  float bias1[4], bias2[4];
#pragma unroll
  for (int cb = 0; cb < 4; cb++) {
    const int n = cb * 16 + l16;
#pragma unroll
    for (int kb = 0; kb < 4; kb++)
      w1f[cb][kb] = *(const s16x8*)&W1t[n * 128 + kb * 32 + quad * 8];
#pragma unroll
    for (int kb = 0; kb < 2; kb++)
      w2f[cb][kb] = *(const s16x8*)&W2t[n * 64 + kb * 32 + quad * 8];
    bias1[cb] = b1[n];
    bias2[cb] = b2[n];
  }

  for (int tile = blockIdx.x; tile < ntiles; tile += gridDim.x) {
    const int eb = tile << 6;

    // stage A: row r = sorted edge eb+r; cols 0..63 = h[dst], 64..127 = h[src]
#pragma unroll
    for (int i = 0; i < 4; i++) {
      int g = t + i * 256; int r = g >> 4, c = g & 15;
      int er = eb + r; if (er >= E) er = E - 1;
      int node = (c >= 8) ? srcS[er] : dstS[er];
      if (c == 0) sDst[r] = node;
      *(uint4*)&sA[r][c * 8] = *(const uint4*)&hb[(size_t)node * 64 + (c & 7) * 8];
    }
    __syncthreads();                               // 1

    // pass 1: hidden = relu([h_i|h_j] @ W1 + b1)
    f32x4 acc[4];
#pragma unroll
    for (int cb = 0; cb < 4; cb++)
      acc[cb] = (f32x4){bias1[cb], bias1[cb], bias1[cb], bias1[cb]};
#pragma unroll
    for (int kb = 0; kb < 4; kb++) {
      s16x8 aF = *(const s16x8*)&sA[wv * 16 + l16][kb * 32 + quad * 8];
#pragma unroll
      for (int cb = 0; cb < 4; cb++)
        acc[cb] = __builtin_amdgcn_mfma_f32_16x16x32_bf16(aF, w1f[cb][kb], acc[cb], 0, 0, 0);
    }
#pragma unroll
    for (int cb = 0; cb < 4; cb++)
#pragma unroll
      for (int reg = 0; reg < 4; reg++)
        sHid[wv * 16 + quad * 4 + reg][cb * 16 + l16] = f2bf(fmaxf(acc[cb][reg], 0.0f));
    __syncthreads();                               // 2 (all sA reads done)

    // pass 2: u = hidden @ W2 + b2
#pragma unroll
    for (int cb = 0; cb < 4; cb++)
      acc[cb] = (f32x4){bias2[cb], bias2[cb], bias2[cb], bias2[cb]};
#pragma unroll
    for (int kb = 0; kb < 2; kb++) {
      s16x8 aF = *(const s16x8*)&sHid[wv * 16 + l16][kb * 32 + quad * 8];
#pragma unroll
      for (int cb = 0; cb < 4; cb++)
        acc[cb] = __builtin_amdgcn_mfma_f32_16x16x32_bf16(aF, w2f[cb][kb], acc[cb], 0, 0, 0);
    }

    // f = 2*tanh(u)-1 -> sRed (f32, aliases sA; safe after barrier 2)
#pragma unroll
    for (int cb = 0; cb < 4; cb++)
#pragma unroll
      for (int reg = 0; reg < 4; reg++) {
        int row = wv * 16 + quad * 4 + reg;
        float f = (eb + row < E) ? tanh_factor(acc[cb][reg]) : 0.0f;
        sRedF[row * 68 + cb * 16 + l16] = f;
      }
    __syncthreads();                               // 3

    // wave-uniform segmented walk: thread owns col j, rows r0..r0+15
    {
      int j = t & 63;
      int r0 = (t >> 6) * 16;
      float run = 0.0f;
      int cur = sDst[r0];
#pragma unroll
      for (int k = 0; k < 16; k++) {
        int r = r0 + k;
        int d = sDst[r];                 // wave-uniform
        float v = sRedF[r * 68 + j];
        if (d != cur) {                  // wave-uniform branch
          atomic_add_f32(&accum[(size_t)cur * 64 + j], run);
          run = 0.0f; cur = d;
        }
        run += v;
      }
      atomic_add_f32(&accum[(size_t)cur * 64 + j], run);
    }
    __syncthreads();                               // 4: sA/sDst reuse
  }
}

// ---------------------------------------------------------------------------
// Node update + BN statistics: h = h * (1 + acc/cnt); accumulate sum/sumsq.
// ---------------------------------------------------------------------------
__global__ __launch_bounds__(256) void node_update_bn(
    float* __restrict__ h, const float* __restrict__ accum,
    const int* __restrict__ cntI, float* __restrict__ bns,
    float* __restrict__ bnq, int N)
{
  const int t = threadIdx.x;
  float ls = 0.0f, lq = 0.0f;
  int total = N * 64;
  for (int idx = blockIdx.x * 256 + t; idx < total; idx += gridDim.x * 256) {
    int n = idx >> 6;
    float cnt = fmaxf((float)cntI[n], 1.0f);
    float v = h[idx] * (1.0f + accum[idx] / cnt);
    h[idx] = v;
    ls += v; lq += v * v;
  }
  __shared__ float ss[256], sq[256];
  ss[t] = ls; sq[t] = lq;
  __syncthreads();
  if (t < 64) {
    float s = ss[t] + ss[t + 64] + ss[t + 128] + ss[t + 192];
    float q = sq[t] + sq[t + 64] + sq[t + 128] + sq[t + 192];
    atomic_add_f32(&bns[t], s);
    atomic_add_f32(&bnq[t], q);
  }
}

// ---------------------------------------------------------------------------
// BN apply + relu (in place); optional bf16 mirror for next MFMA layer.
// ---------------------------------------------------------------------------
__global__ __launch_bounds__(256) void bn_apply_relu(
    float* __restrict__ d, const float* __restrict__ bns,
    const float* __restrict__ bnq, const float* __restrict__ gam,
    const float* __restrict__ bet, unsigned short* __restrict__ hbOut,
    int total, int cmask, float invRows)
{
  for (int idx = blockIdx.x * 256 + threadIdx.x; idx < total;
       idx += gridDim.x * 256) {
    int c = idx & cmask;
    float m = bns[c] * invRows;
    float var = bnq[c] * invRows - m * m;
    float sc = gam[c] * rsqrtf(var + 1e-5f);
    float v = fmaxf((d[idx] - m) * sc + bet[c], 0.0f);
    d[idx] = v;
    if (hbOut) hbOut[idx] = f2bf(v);
  }
}

// ---------------------------------------------------------------------------
// Classifier matmul (rows x K @ K x C) + bias, with BN stats.
// ---------------------------------------------------------------------------
__global__ __launch_bounds__(256) void clf_mm_bn(
    const float* __restrict__ in, const float* __restrict__ W,
    const float* __restrict__ b, float* __restrict__ out,
    float* __restrict__ bns, float* __restrict__ bnq,
    int rows, int K, int cshift)
{
  const int t = threadIdx.x;
  const int C = 1 << cshift;
  int total = rows << cshift;
  float ls = 0.0f, lq = 0.0f;
  for (int idx = blockIdx.x * 256 + t; idx < total; idx += gridDim.x * 256) {
    int n = idx >> cshift;
    int c = idx & (C - 1);
    float acc = b[c];
#pragma unroll 8
    for (int k = 0; k < K; k++) acc = fmaf(in[n * K + k], W[(k << cshift) + c], acc);
    out[idx] = acc;
    ls += acc; lq += acc * acc;
  }
  __shared__ float ss[256], sq[256];
  ss[t] = ls; sq[t] = lq;
  __syncthreads();
  if (t < C) {
    float s = 0.0f, q = 0.0f;
    for (int i = t; i < 256; i += C) { s += ss[i]; q += sq[i]; }
    atomic_add_f32(&bns[t], s);
    atomic_add_f32(&bnq[t], q);
  }
}

__global__ __launch_bounds__(256) void clf_final(
    const float* __restrict__ z2, const float* __restrict__ W3,
    const float* __restrict__ b3, float* __restrict__ out, int rows)
{
  int n = blockIdx.x * 256 + threadIdx.x;
  if (n >= rows) return;
  float acc = b3[0];
#pragma unroll
  for (int k = 0; k < 32; k++) acc = fmaf(z2[n * 32 + k], W3[k], acc);
  out[n] = acc;
}

// ---------------------------------------------------------------------------
extern "C" void kernel_launch(void* const* d_in, const int* in_sizes, int n_in,
                              void* d_out, int out_size, void* d_ws, size_t ws_size,
                              hipStream_t stream)
{
  const float* x    = (const float*)d_in[0];
  const int*   ei   = (const int*)  d_in[1];
  const float* dts  = (const float*)d_in[2];
  const float* freq = (const float*)d_in[4];
  const float* phs  = (const float*)d_in[5];
  const float* tW1  = (const float*)d_in[6];
  const float* tb1  = (const float*)d_in[7];
  const float* tW2  = (const float*)d_in[8];
  const float* tb2  = (const float*)d_in[9];
  const float* pW   = (const float*)d_in[10];
  const float* pb   = (const float*)d_in[11];
  const float* sW1  = (const float*)d_in[12];
  const float* sb1  = (const float*)d_in[13];
  const float* sW2  = (const float*)d_in[14];
  const float* sb2  = (const float*)d_in[15];
  const float* bng  = (const float*)d_in[16];
  const float* bnb  = (const float*)d_in[17];
  const float* cW1  = (const float*)d_in[18];
  const float* cb1  = (const float*)d_in[19];
  const float* cg1  = (const float*)d_in[20];
  const float* cbb1 = (const float*)d_in[21];
  const float* cW2  = (const float*)d_in[22];
  const float* cb2  = (const float*)d_in[23];
  const float* cg2  = (const float*)d_in[24];
  const float* cbb2 = (const float*)d_in[25];
  const float* cW3  = (const float*)d_in[26];
  const float* cb3  = (const float*)d_in[27];
  float* out = (float*)d_out;

  const int N = in_sizes[0] / 17;
  const int E = in_sizes[1] / 2;
  const int B = out_size;

  // workspace layout
  float* ws     = (float*)d_ws;
  float* h      = ws;                            // N*64
  float* acc2   = h    + (size_t)N * 64;         // N*64
  float* acc1   = acc2 + (size_t)N * 64;         // N*17 (z1/z2 alias)
  float* z1     = acc1;
  float* z2     = z1 + (size_t)B * 64;
  float* bns    = acc1 + (size_t)N * 17;         // 64
  float* bnq    = bns + 64;                      // 64
  unsigned short* hb  = (unsigned short*)(bnq + 64);   // N*64 bf16
  unsigned short* W1t = hb + (size_t)N * 64;           // 2*64*128
  unsigned short* W2t = W1t + 2 * 64 * 128;            // 2*64*64
  int*   cntI   = (int*)(W2t + 2 * 64 * 64);     // N
  int*   cursor = cntI + N;                      // N
  int*   bsum   = cursor + N;                    // 512
  int*   dstS   = bsum + 512;                    // E
  int*   srcS   = dstS + (size_t)E;              // E
  float* dtsS   = (float*)(srcS + (size_t)E);    // E
  size_t needed = (size_t)((char*)(dtsS + E) - (char*)d_ws);
  if (ws_size < needed) return;  // fail visibly (output stays poisoned)

  const int ntiles = (E + 63) / 64;
  const int NB = (N + 255) / 256;
  if (NB > 512) return;

  // ---- counting sort by dst (also yields counts) ----
  hipMemsetAsync(cntI, 0, (size_t)N * 4, stream);
  hipMemsetAsync(acc1, 0, (size_t)N * 17 * 4, stream);
  k_hist<<<(E + 255) / 256, 256, 0, stream>>>(ei, cntI, E);
  k_scan_block<<<NB, 256, 0, stream>>>(cntI, cursor, bsum, N);
  k_scan_bsum<<<1, 512, 0, stream>>>(bsum, NB);
  k_scan_add<<<NB, 256, 0, stream>>>(cursor, bsum, N);
  k_scatter<<<(E + 255) / 256, 256, 0, stream>>>(ei, dts, cursor, dstS, srcS, dtsS, E);
  prep_w<<<64, 256, 0, stream>>>(sW1, sW2, W1t, W2t);

  // ---- phase 1 ----
  phase1_edge<<<(E + 255) / 256, 256, 0, stream>>>(
      x, dstS, srcS, dtsS, freq, phs, tW1, tb1, tW2, tb2, acc1, E);
  phase1_node<<<(N + 3) / 4, 256, 0, stream>>>(x, acc1, cntI, pW, pb, h, hb, N);

  // ---- phase 2: L = 2 message-passing + BN layers ----
  for (int l = 0; l < 2; l++) {
    hipMemsetAsync(acc2, 0, (size_t)N * 64 * 4, stream);
    hipMemsetAsync(bns, 0, 128 * 4, stream);
    phase2_edge<<<768, 256, 0, stream>>>(
        hb, dstS, srcS, W1t + (size_t)l * 64 * 128, sb1 + l * 64,
        W2t + (size_t)l * 64 * 64, sb2 + l * 64, acc2, E, ntiles);
    node_update_bn<<<1024, 256, 0, stream>>>(h, acc2, cntI, bns, bnq, N);
    bn_apply_relu<<<2048, 256, 0, stream>>>(
        h, bns, bnq, bng + l * 64, bnb + l * 64, hb, N * 64, 63, 1.0f / (float)N);
  }

  // ---- classifier on first B rows of h ----
  hipMemsetAsync(bns, 0, 128 * 4, stream);
  clf_mm_bn<<<2500, 256, 0, stream>>>(h, cW1, cb1, z1, bns, bnq, B, 64, 6);
  bn_apply_relu<<<1024, 256, 0, stream>>>(z1, bns, bnq, cg1, cbb1, nullptr,
                                          B * 64, 63, 1.0f / (float)B);
  hipMemsetAsync(bns, 0, 128 * 4, stream);
  clf_mm_bn<<<1250, 256, 0, stream>>>(z1, cW2, cb2, z2, bns, bnq, B, 64, 5);
  bn_apply_relu<<<512, 256, 0, stream>>>(z2, bns, bnq, cg2, cbb2, nullptr,
                                         B * 32, 31, 1.0f / (float)B);
  clf_final<<<(B + 255) / 256, 256, 0, stream>>>(z2, cW3, cb3, out, B);
}